// Round 14
// baseline (282.639 us; speedup 1.0000x reference)
//
#include <hip/hip_runtime.h>
#include <stdint.h>

// Problem constants
constexpr int kD  = 2048;   // D_ATTN
constexpr int kDS = 64;     // D_STATE
constexpr int kNT = 2048;   // T
constexpr int kM  = 8 * kNT;            // 16384 rows
constexpr int kOutElems = kM * kD;      // 33554432

typedef __attribute__((ext_vector_type(8))) short short8;
typedef __attribute__((ext_vector_type(8))) unsigned short bfu8;
typedef __attribute__((ext_vector_type(4))) float f32x4;

__device__ __forceinline__ unsigned short f2bf(float f) {
  unsigned int u = __float_as_uint(f);
  return (unsigned short)((u + 0x7FFFu + ((u >> 16) & 1u)) >> 16);
}
__device__ __forceinline__ float bf2f(unsigned short b) {
  return __uint_as_float(((unsigned int)b) << 16);
}

__device__ __forceinline__ void gload16(const void* g, void* l) {
  __builtin_amdgcn_global_load_lds((__attribute__((address_space(1))) void*)g,
                                   (__attribute__((address_space(3))) void*)l,
                                   16, 0, 0);
}

// ---------------- convert kernels ----------------
__global__ void k_cvt(const float* __restrict__ src, unsigned short* __restrict__ dst, int n8) {
  int i8 = blockIdx.x * 256 + threadIdx.x;
  if (i8 >= n8) return;
  const f32x4* s = (const f32x4*)(src + (size_t)i8 * 8);
  f32x4 v0 = s[0], v1 = s[1];
  bfu8 o;
  o[0] = f2bf(v0[0]); o[1] = f2bf(v0[1]); o[2] = f2bf(v0[2]); o[3] = f2bf(v0[3]);
  o[4] = f2bf(v1[0]); o[5] = f2bf(v1[1]); o[6] = f2bf(v1[2]); o[7] = f2bf(v1[3]);
  *(bfu8*)(dst + (size_t)i8 * 8) = o;
}

// Interleave W_key/W_value rows, scale by gamma -> G (128x2048 bf16);
// also cg[s]=sum(gamma*W), cb[s]=sum(beta*W) per interleaved row (exact f32).
__launch_bounds__(256)
__global__ void k_cvt_kv_g(const float* __restrict__ wk, const float* __restrict__ wv,
                           const float* __restrict__ gamma, const float* __restrict__ beta,
                           unsigned short* __restrict__ dst, float2* __restrict__ cgb) {
  int b = blockIdx.x;            // dst row 0..127
  int tid = threadIdx.x;         // 256 threads, 8 elems each
  int s = b >> 1;
  const float* src = (b & 1) ? wv : wk;
  int d0 = tid * 8;
  const f32x4* p = (const f32x4*)(src + (size_t)s * kD + d0);
  f32x4 v0 = p[0], v1 = p[1];
  f32x4 g0 = *(const f32x4*)&gamma[d0], g1 = *(const f32x4*)&gamma[d0 + 4];
  f32x4 b0 = *(const f32x4*)&beta[d0],  b1 = *(const f32x4*)&beta[d0 + 4];
  bfu8 o;
  float sg = 0.f, sb = 0.f;
#pragma unroll
  for (int j = 0; j < 4; ++j) {
    float gw0 = g0[j] * v0[j], gw1 = g1[j] * v1[j];
    o[j] = f2bf(gw0); o[j + 4] = f2bf(gw1);
    sg += gw0 + gw1;
    sb += b0[j] * v0[j] + b1[j] * v1[j];
  }
  *(bfu8*)(dst + (size_t)b * kD + d0) = o;
#pragma unroll
  for (int d = 1; d < 64; d <<= 1) { sg += __shfl_xor(sg, d); sb += __shfl_xor(sb, d); }
  __shared__ float gg[4], bb[4];
  if ((tid & 63) == 0) { gg[tid >> 6] = sg; bb[tid >> 6] = sb; }
  __syncthreads();
  if (tid == 0)
    cgb[b] = make_float2(gg[0] + gg[1] + gg[2] + gg[3], bb[0] + bb[1] + bb[2] + bb[3]);
}

// ---------------- 256x256 m201-template shift GEMM ----------------
// x_shift = (roll(x) @ Wsh^T)*g + x*(1-g), written as bf16.
// Phase = {ds_reads; stage; [lgkm(8)]; BAR; lgkm(0); setprio-MFMA; BAR}.
// Stage plan tile t: ph0 B1(t+1)->buf^1; ph1 A0(t+2)->buf; ph3 A1(t+2)+B0(t+2)->buf.
// ONE vmcnt(6) per K-tile (end of ph3): retires exactly tile t+1's 4 halves,
// keeps 3 half-tiles (t+2) in flight. FIFO verified; tail uses vmcnt(0).
#define MM(x,y,z) __builtin_amdgcn_mfma_f32_16x16x32_bf16(x,y,z,0,0,0)
#define BAR __builtin_amdgcn_s_barrier()
#define WAITV_(N) asm volatile("s_waitcnt vmcnt(" #N ")" ::: "memory")
#define WAITV(N) WAITV_(N)
#define WAITL asm volatile("s_waitcnt lgkmcnt(0)")
#define WAITL8 asm volatile("s_waitcnt lgkmcnt(8)")
#define NOWV (void)0

#define STAGEA_TO(BUF,H,Q,KT) gload16(aS + (size_t)(((H)*64+(Q)*128)*2048) + (KT), \
                                      smem + (BUF)*32768 + ((H)*64+(Q)*128)*64 + ldsAst)
#define STAGEB_TO(BUF,H,Q,KT) gload16(bS + (size_t)(((H)*32+(Q)*128)*2048) + (KT), \
                                      smem + (BUF)*32768 + 16384 + (H)*2048 + (Q)*8192 + ldsBst)

#define RDA(CUR,H,MF,KS) (*(const short8*)(smem + (CUR)*32768 + ardb + (H)*4096 + (MF)*1024 + colrd##KS))
#define RDB(CUR,H,NF,KS) (*(const short8*)(smem + (CUR)*32768 + 16384 + brdb + (H)*2048 + (NF)*1024 + colrd##KS))

#define RD_A(CUR,H) \
  a[0][0]=RDA(CUR,H,0,0); a[0][1]=RDA(CUR,H,0,1); \
  a[1][0]=RDA(CUR,H,1,0); a[1][1]=RDA(CUR,H,1,1); \
  a[2][0]=RDA(CUR,H,2,0); a[2][1]=RDA(CUR,H,2,1); \
  a[3][0]=RDA(CUR,H,3,0); a[3][1]=RDA(CUR,H,3,1)
#define RD_B(CUR,H,BV) \
  BV[0][0]=RDB(CUR,H,0,0); BV[0][1]=RDB(CUR,H,0,1); \
  BV[1][0]=RDB(CUR,H,1,0); BV[1][1]=RDB(CUR,H,1,1)

// k-outer MFMA order (same-acc distance 8); per-acc addend order k0,k1 preserved.
#define MF16(MH, B, NB) \
  __builtin_amdgcn_s_setprio(1); \
  acc[(MH)*4+0][(NB)+0] = MM(a[0][0], B[0][0], acc[(MH)*4+0][(NB)+0]); \
  acc[(MH)*4+0][(NB)+1] = MM(a[0][0], B[1][0], acc[(MH)*4+0][(NB)+1]); \
  acc[(MH)*4+1][(NB)+0] = MM(a[1][0], B[0][0], acc[(MH)*4+1][(NB)+0]); \
  acc[(MH)*4+1][(NB)+1] = MM(a[1][0], B[1][0], acc[(MH)*4+1][(NB)+1]); \
  acc[(MH)*4+2][(NB)+0] = MM(a[2][0], B[0][0], acc[(MH)*4+2][(NB)+0]); \
  acc[(MH)*4+2][(NB)+1] = MM(a[2][0], B[1][0], acc[(MH)*4+2][(NB)+1]); \
  acc[(MH)*4+3][(NB)+0] = MM(a[3][0], B[0][0], acc[(MH)*4+3][(NB)+0]); \
  acc[(MH)*4+3][(NB)+1] = MM(a[3][0], B[1][0], acc[(MH)*4+3][(NB)+1]); \
  acc[(MH)*4+0][(NB)+0] = MM(a[0][1], B[0][1], acc[(MH)*4+0][(NB)+0]); \
  acc[(MH)*4+0][(NB)+1] = MM(a[0][1], B[1][1], acc[(MH)*4+0][(NB)+1]); \
  acc[(MH)*4+1][(NB)+0] = MM(a[1][1], B[0][1], acc[(MH)*4+1][(NB)+0]); \
  acc[(MH)*4+1][(NB)+1] = MM(a[1][1], B[1][1], acc[(MH)*4+1][(NB)+1]); \
  acc[(MH)*4+2][(NB)+0] = MM(a[2][1], B[0][1], acc[(MH)*4+2][(NB)+0]); \
  acc[(MH)*4+2][(NB)+1] = MM(a[2][1], B[1][1], acc[(MH)*4+2][(NB)+1]); \
  acc[(MH)*4+3][(NB)+0] = MM(a[3][1], B[0][1], acc[(MH)*4+3][(NB)+0]); \
  acc[(MH)*4+3][(NB)+1] = MM(a[3][1], B[1][1], acc[(MH)*4+3][(NB)+1]); \
  __builtin_amdgcn_s_setprio(0)

// Quadrant phases (2 barriers each, m201 style)
#define QH0(CUR, SB1, KB1) \
  RD_A(CUR,0); RD_B(CUR,0,b0); \
  if (SB1) { STAGEB_TO((CUR)^1,1,0,KB1); STAGEB_TO((CUR)^1,1,1,KB1); } \
  WAITL8; BAR; WAITL; MF16(0, b0, 0); BAR

#define QH1(CUR, SA, KT2) \
  RD_B(CUR,1,b1); \
  if (SA) { STAGEA_TO(CUR,0,0,KT2); STAGEA_TO(CUR,0,1,KT2); } \
  BAR; WAITL; MF16(0, b1, 2); BAR

#define QH2(CUR) \
  RD_A(CUR,1); \
  BAR; WAITL; MF16(1, b0, 0); BAR

#define QH3(CUR, SA, KT2, WV) \
  if (SA) { STAGEA_TO(CUR,1,0,KT2); STAGEA_TO(CUR,1,1,KT2); \
            STAGEB_TO(CUR,0,0,KT2); STAGEB_TO(CUR,0,1,KT2); } \
  BAR; WAITL; MF16(1, b1, 2); WV; BAR

#define KTILE(CUR, KB1, KT2, SB1, SA, WV) \
  QH0(CUR, SB1, KB1); QH1(CUR, SA, KT2); QH2(CUR); QH3(CUR, SA, KT2, WV)

__global__ __launch_bounds__(512, 2)
void k_gemm_shift8(const unsigned short* __restrict__ A,   // 16384x2048 bf16 x
                   const unsigned short* __restrict__ Bw,  // 2048x2048 bf16 W_shift
                   const float* __restrict__ gate,
                   unsigned short* __restrict__ out) {     // x_shift bf16
  __shared__ __align__(16) unsigned char smem_raw[131072];
  unsigned short* smem = (unsigned short*)smem_raw;

  const int tid = threadIdx.x;
  const int lane = tid & 63;
  const int w = tid >> 6;
  const int wr = w >> 2, wc = w & 3;
  const int lr = lane & 15, lq = lane >> 4;
  const int bid = blockIdx.x;
  const int nblk = bid & 7, mblk = bid >> 3;   // XCD keeps one N-panel L2-resident
  const int m0 = mblk * 256, n0 = nblk * 256;

  // staging addressing (pre-swizzled global source; linear LDS dest)
  const int r0 = tid >> 3;                                   // 0..63
  const int colel = ((tid & 7) * 8) ^ (((tid >> 3) & 7) << 3);
  const unsigned short* aS = A + (size_t)((m0 ^ 1024) + r0) * 2048 + colel;  // roll fused
  const unsigned short* bS = Bw + (size_t)(n0 + ((tid >> 8) << 6) + (r0 & 31)) * 2048 + colel;
  const int ldsAst = tid * 8;
  const int ldsBst = ((tid >> 8) << 12) + (tid & 255) * 8;

  // ds_read addressing (swizzled)
  const int ardb = (wr * 128 + lr) * 64;
  const int brdb = (wc * 64 + lr) * 64;
  const int colrd0 = (lq * 8) ^ ((lr & 7) << 3);
  const int colrd1 = (32 + lq * 8) ^ ((lr & 7) << 3);

  short8 a[4][2], b0[2][2], b1[2][2];
  f32x4 acc[8][4] = {};

  // prologue (FIFO order): tile0 {A0,A1,B0,B1} -> buf0; tile1 {A0,A1,B0} -> buf1
  STAGEA_TO(0,0,0,0); STAGEA_TO(0,0,1,0);
  STAGEA_TO(0,1,0,0); STAGEA_TO(0,1,1,0);
  STAGEB_TO(0,0,0,0); STAGEB_TO(0,0,1,0);
  STAGEB_TO(0,1,0,0); STAGEB_TO(0,1,1,0);
  STAGEA_TO(1,0,0,64); STAGEA_TO(1,0,1,64);
  STAGEA_TO(1,1,0,64); STAGEA_TO(1,1,1,64);
  STAGEB_TO(1,0,0,64); STAGEB_TO(1,0,1,64);
  WAITV(6); BAR;

  int kb1 = 64, kt2 = 128;
  for (int j = 0; j < 15; ++j) {     // tiles 0..29
    KTILE(0, kb1, kt2, 1, 1, WAITV(6)); kb1 += 64; kt2 += 64;
    KTILE(1, kb1, kt2, 1, 1, WAITV(6)); kb1 += 64; kt2 += 64;
  }
  // tile 30 (CUR=0): stage only B1(31); retire everything at end
  KTILE(0, 1984, 0, 1, 0, WAITV(0));
  // tile 31 (CUR=1): pure drain
  KTILE(1, 0, 0, 0, 0, NOWV);

  // ---- epilogue: LDS transpose + fused sigmoid-gate blend, bf16 stores ----
  float* cbuf = (float*)smem_raw;                 // 64 x 260 f32
#pragma unroll
  for (int q = 0; q < 4; ++q) {
    __syncthreads();
    if (wr == (q >> 1)) {
#pragma unroll
      for (int mm = 0; mm < 4; ++mm) {
#pragma unroll
        for (int nf = 0; nf < 4; ++nf) {
#pragma unroll
          for (int i = 0; i < 4; ++i) {
            int rl = mm * 16 + lq * 4 + i;
            int cl = wc * 64 + nf * 16 + lr;
            cbuf[rl * 260 + cl] = acc[(q & 1) * 4 + mm][nf][i];
          }
        }
      }
    }
    __syncthreads();
#pragma unroll
    for (int it = 0; it < 4; ++it) {
      int idx = tid + it * 512;
      int rl = idx >> 5, cb = (idx & 31) * 8;
      int gr = m0 + q * 64 + rl, gc = n0 + cb;
      f32x4 c0 = *(const f32x4*)&cbuf[rl * 260 + cb];
      f32x4 c1 = *(const f32x4*)&cbuf[rl * 260 + cb + 4];
      f32x4 g0 = *(const f32x4*)&gate[gc];
      f32x4 g1 = *(const f32x4*)&gate[gc + 4];
      bfu8 xv = *(const bfu8*)(A + (size_t)gr * 2048 + gc);
      bfu8 o;
#pragma unroll
      for (int jj = 0; jj < 4; ++jj) {
        float g = 1.f / (1.f + __expf(-g0[jj]));
        o[jj] = f2bf(c0[jj] * g + bf2f(xv[jj]) * (1.f - g));
        float h = 1.f / (1.f + __expf(-g1[jj]));
        o[jj + 4] = f2bf(c1[jj] * h + bf2f(xv[jj + 4]) * (1.f - h));
      }
      *(bfu8*)(out + (size_t)gr * 2048 + gc) = o;
    }
  }
}

// ---------------- per-row LN stats from x_shift: (mean, rstd) ----------------
__launch_bounds__(256)
__global__ void k_stats(const unsigned short* __restrict__ xs, float2* __restrict__ stats) {
  int m = blockIdx.x;
  int tid = threadIdx.x;
  bfu8 v = *(const bfu8*)(xs + (size_t)m * kD + tid * 8);
  float s = 0.f, q = 0.f;
#pragma unroll
  for (int j = 0; j < 8; ++j) { float f = bf2f(v[j]); s += f; q += f * f; }
#pragma unroll
  for (int d = 1; d < 64; d <<= 1) { s += __shfl_xor(s, d); q += __shfl_xor(q, d); }
  __shared__ float ss[4], qq[4];
  if ((tid & 63) == 0) { ss[tid >> 6] = s; qq[tid >> 6] = q; }
  __syncthreads();
  if (tid == 0) {
    s = ss[0] + ss[1] + ss[2] + ss[3];
    q = qq[0] + qq[1] + qq[2] + qq[3];
    float mean = s * (1.f / kD);
    float var = q * (1.f / kD) - mean * mean;
    stats[m] = make_float2(mean, rsqrtf(var + 1e-5f));
  }
}

// ---------------- fused kv GEMM on x_shift with affine LN correction ----------------
__launch_bounds__(256, 2)
__global__ void k_gemm_kv_f(const unsigned short* __restrict__ A,     // x_shift bf16
                            const unsigned short* __restrict__ Bw,    // G = gamma*Wkv interleaved
                            const float2* __restrict__ stats,         // per-row (mu, rstd)
                            const float2* __restrict__ cgb,           // per-col (cg, cb)
                            const float* __restrict__ tfirst,
                            float* __restrict__ wkv) {
  __shared__ __align__(16) unsigned short As[32 * 32];
  __shared__ __align__(16) unsigned short Bs[128 * 32];
  __shared__ float2 rowst[32];
  const int tid = threadIdx.x;
  const int lane = tid & 63;
  const int wcv = tid >> 6;
  const int m0 = blockIdx.x * 32;
  const int lr = lane & 15, lk = (lane >> 4) << 3;
  const int c1 = tid, c2 = tid + 256;

  if (tid < 32) rowst[tid] = stats[m0 + tid];

  const unsigned short* ga = A + (size_t)(m0 + (tid >> 2)) * kD + ((tid & 3) << 3);
  const unsigned short* gb0 = Bw + (size_t)(c1 >> 2) * kD + ((c1 & 3) << 3);
  const unsigned short* gb1 = Bw + (size_t)(c2 >> 2) * kD + ((c2 & 3) << 3);
  unsigned short* la = As + tid * 8;
  unsigned short* lb0 = Bs + c1 * 8;
  unsigned short* lb1 = Bs + c2 * 8;

  f32x4 acc[2][2] = {};

  for (int kt = 0; kt < kD; kt += 32) {
    __syncthreads();
    if (tid < 128) gload16(ga + kt, la);
    gload16(gb0 + kt, lb0);
    gload16(gb1 + kt, lb1);
    __syncthreads();
    short8 af[2], bf[2];
#pragma unroll
    for (int mf = 0; mf < 2; ++mf)
      af[mf] = *(const short8*)&As[(mf * 16 + lr) * 32 + lk];
#pragma unroll
    for (int nf = 0; nf < 2; ++nf)
      bf[nf] = *(const short8*)&Bs[(wcv * 32 + nf * 16 + lr) * 32 + lk];
#pragma unroll
    for (int mf = 0; mf < 2; ++mf)
#pragma unroll
      for (int nf = 0; nf < 2; ++nf)
        acc[mf][nf] = __builtin_amdgcn_mfma_f32_16x16x32_bf16(af[mf], bf[nf], acc[mf][nf], 0, 0, 0);
  }

  const int fq = lane >> 4, fr = lane & 15;
#pragma unroll
  for (int mf = 0; mf < 2; ++mf) {
#pragma unroll
    for (int nf = 0; nf < 2; ++nf) {
      int c = wcv * 32 + nf * 16 + fr;
      float2 gc = cgb[c];
#pragma unroll
      for (int i = 0; i < 4; ++i) {
        int rloc = mf * 16 + fq * 4 + i;
        float2 st = rowst[rloc];
        float val = st.y * (acc[mf][nf][i] - st.x * gc.x) + gc.y;  // LN-corrected k or v
        float other = __shfl_xor(val, 1);
        if (!(c & 1)) {
          int s = c >> 1;
          float sk = 1.f / (1.f + expf(-val));
          float u = expf(tfirst[s]);
          wkv[(size_t)(m0 + rloc) * kDS + s] = expf(-u * sk) * other;
        }
      }
    }
  }
}

// ---------------- chunked linear scan (chunk=64, warmup 256) -> bf16 states ----------------
__global__ void k_scan(const float* __restrict__ wkv, const float* __restrict__ tdec,
                       unsigned short* __restrict__ states, float* __restrict__ last_state) {
  int chunk = blockIdx.x;   // 0..31
  int b = blockIdx.y;       // 0..7
  int s = threadIdx.x;      // 0..63
  float w = expf(tdec[s]);
  int t1 = chunk * 64;
  int warm = t1 < 256 ? t1 : 256;
  const float* base = wkv + (size_t)b * kNT * kDS + s;
  unsigned short* sbase = states + (size_t)b * kNT * kDS + s;
  float st = 0.f;
#pragma unroll 4
  for (int t = t1 - warm; t < t1; ++t) st = fmaf(st, w, base[(size_t)t * kDS]);
#pragma unroll 4
  for (int t = t1; t < t1 + 64; ++t) {
    st = fmaf(st, w, base[(size_t)t * kDS]);
    sbase[(size_t)t * kDS] = f2bf(st);
  }
  if (chunk == 31) last_state[b * kDS + s] = st;
}

// ---------------- output GEMM (bf16 MFMA, f32 out): 128x128 tiles, K=64 ----------------
__launch_bounds__(256, 3)
__global__ void k_out_gemm(const unsigned short* __restrict__ states,  // 16384x64 bf16
                           const unsigned short* __restrict__ Wo,      // 2048x64 bf16
                           float* __restrict__ out) {
  __shared__ __align__(16) unsigned char sraw[33792];
  unsigned short* As = (unsigned short*)sraw;          // 128*64 bf16 = 16384 B
  unsigned short* Bs = As + 8192;                      // 16384 B
  float* cbuf = (float*)sraw;                          // aliases As/Bs after fragment reads
  const int tid = threadIdx.x;
  const int lane = tid & 63;
  const int w = tid >> 6;
  const int wr = w >> 1, wc = w & 1;
  const int lr = lane & 15, lq = lane >> 4;
  const int n0 = blockIdx.x * 128;
  const int m0 = blockIdx.y * 128;

  const int sr0 = tid >> 3;
  const int scol = ((tid & 7) * 8) ^ (((tid >> 3) & 7) << 3);
#pragma unroll
  for (int rd = 0; rd < 4; ++rd) {
    gload16(states + (size_t)(m0 + sr0 + rd * 32) * 64 + scol, As + tid * 8 + rd * 2048);
    gload16(Wo + (size_t)(n0 + sr0 + rd * 32) * 64 + scol, Bs + tid * 8 + rd * 2048);
  }
  __syncthreads();

  short8 a[4][2], b[4][2];
#pragma unroll
  for (int mf = 0; mf < 4; ++mf) {
#pragma unroll
    for (int ks = 0; ks < 2; ++ks) {
      int col = (ks * 32 + lq * 8) ^ ((lr & 7) << 3);
      a[mf][ks] = *(const short8*)&As[(wr * 64 + mf * 16 + lr) * 64 + col];
      b[mf][ks] = *(const short8*)&Bs[(wc * 64 + mf * 16 + lr) * 64 + col];
    }
  }
  f32x4 acc[4][4] = {};
#pragma unroll
  for (int mf = 0; mf < 4; ++mf)
#pragma unroll
    for (int nf = 0; nf < 4; ++nf) {
      acc[mf][nf] = __builtin_amdgcn_mfma_f32_16x16x32_bf16(a[mf][0], b[nf][0], acc[mf][nf], 0, 0, 0);
      acc[mf][nf] = __builtin_amdgcn_mfma_f32_16x16x32_bf16(a[mf][1], b[nf][1], acc[mf][nf], 0, 0, 0);
    }

#pragma unroll
  for (int q = 0; q < 2; ++q) {
    __syncthreads();
    if (wr == q) {
#pragma unroll
      for (int mf = 0; mf < 4; ++mf)
#pragma unroll
        for (int nf = 0; nf < 4; ++nf)
#pragma unroll
          for (int i = 0; i < 4; ++i) {
            int rl = mf * 16 + lq * 4 + i;
            int cl = wc * 64 + nf * 16 + lr;
            cbuf[rl * 132 + cl] = acc[mf][nf][i];
          }
    }
    __syncthreads();
#pragma unroll
    for (int it = 0; it < 8; ++it) {
      int idx = tid + it * 256;
      int rl = idx >> 5, cb = (idx & 31) * 4;
      *(f32x4*)&out[(size_t)(m0 + q * 64 + rl) * kD + n0 + cb] = *(const f32x4*)&cbuf[rl * 132 + cb];
    }
  }
}

// ---------------- launcher ----------------
extern "C" void kernel_launch(void* const* d_in, const int* in_sizes, int n_in,
                              void* d_out, int out_size, void* d_ws, size_t ws_size,
                              hipStream_t stream) {
  const float* x    = (const float*)d_in[0];
  const float* Wk   = (const float*)d_in[1];
  const float* Wv   = (const float*)d_in[2];
  const float* Wo   = (const float*)d_in[3];
  const float* Wsh  = (const float*)d_in[4];
  const float* gate = (const float*)d_in[5];
  const float* tdec = (const float*)d_in[6];
  const float* tfir = (const float*)d_in[7];
  const float* lng  = (const float*)d_in[8];
  const float* lnb  = (const float*)d_in[9];
  float* out = (float*)d_out;
  char* ws = (char*)d_ws;

  unsigned short* xbf   = (unsigned short*)(ws);               // 67108864 B (x bf16)
  unsigned short* wshbf = (unsigned short*)(ws + 67108864);    //  8388608 B
  unsigned short* wkvbf = (unsigned short*)(ws + 75497472);    //   524288 B (G interleaved)
  float* wkvf           = (float*)(ws + 76021760);             //  4194304 B
  unsigned short* stbf  = (unsigned short*)(ws + 80216064);    //  2097152 B (states bf16)
  unsigned short* wobf  = (unsigned short*)(ws + 82313216);    //   262144 B (Wo bf16)
  float2* statsp        = (float2*)(ws + 82575360);            //   131072 B (mu, rstd per row)
  float2* cgbp          = (float2*)(ws + 82706432);            //     1024 B (cg, cb per col)

  k_cvt<<<16384, 256, 0, stream>>>(x, xbf, 4194304);
  k_cvt<<<2048, 256, 0, stream>>>(Wsh, wshbf, 524288);
  k_cvt<<<64, 256, 0, stream>>>(Wo, wobf, 16384);
  k_cvt_kv_g<<<128, 256, 0, stream>>>(Wk, Wv, lng, lnb, wkvbf, cgbp);

  // x_shift (bf16) staged in d_out, overwritten later by the final output GEMM
  k_gemm_shift8<<<512, 512, 0, stream>>>(xbf, wshbf, gate, (unsigned short*)out);
  k_stats<<<16384, 256, 0, stream>>>((const unsigned short*)out, statsp);
  k_gemm_kv_f<<<512, 256, 0, stream>>>((const unsigned short*)out, wkvbf, statsp, cgbp, tfir, wkvf);
  k_scan<<<dim3(32, 8), 64, 0, stream>>>(wkvf, tdec, stbf, out + kOutElems);
  k_out_gemm<<<dim3(16, 128), 256, 0, stream>>>(stbf, wobf, out);
}

// Round 15
// 276.398 us; speedup vs baseline: 1.0226x; 1.0226x over previous
//
#include <hip/hip_runtime.h>
#include <stdint.h>

// Problem constants
constexpr int kD  = 2048;   // D_ATTN
constexpr int kDS = 64;     // D_STATE
constexpr int kNT = 2048;   // T
constexpr int kM  = 8 * kNT;            // 16384 rows
constexpr int kOutElems = kM * kD;      // 33554432

typedef __attribute__((ext_vector_type(8))) short short8;
typedef __attribute__((ext_vector_type(8))) unsigned short bfu8;
typedef __attribute__((ext_vector_type(4))) float f32x4;

__device__ __forceinline__ unsigned short f2bf(float f) {
  unsigned int u = __float_as_uint(f);
  return (unsigned short)((u + 0x7FFFu + ((u >> 16) & 1u)) >> 16);
}
__device__ __forceinline__ float bf2f(unsigned short b) {
  return __uint_as_float(((unsigned int)b) << 16);
}

__device__ __forceinline__ void gload16(const void* g, void* l) {
  __builtin_amdgcn_global_load_lds((__attribute__((address_space(1))) void*)g,
                                   (__attribute__((address_space(3))) void*)l,
                                   16, 0, 0);
}

// ---------------- convert kernels ----------------
__global__ void k_cvt(const float* __restrict__ src, unsigned short* __restrict__ dst, int n8) {
  int i8 = blockIdx.x * 256 + threadIdx.x;
  if (i8 >= n8) return;
  const f32x4* s = (const f32x4*)(src + (size_t)i8 * 8);
  f32x4 v0 = s[0], v1 = s[1];
  bfu8 o;
  o[0] = f2bf(v0[0]); o[1] = f2bf(v0[1]); o[2] = f2bf(v0[2]); o[3] = f2bf(v0[3]);
  o[4] = f2bf(v1[0]); o[5] = f2bf(v1[1]); o[6] = f2bf(v1[2]); o[7] = f2bf(v1[3]);
  *(bfu8*)(dst + (size_t)i8 * 8) = o;
}

// Interleave W_key/W_value rows, scale by gamma -> G (128x2048 bf16);
// also cg[s]=sum(gamma*W), cb[s]=sum(beta*W) per interleaved row (exact f32).
__launch_bounds__(256)
__global__ void k_cvt_kv_g(const float* __restrict__ wk, const float* __restrict__ wv,
                           const float* __restrict__ gamma, const float* __restrict__ beta,
                           unsigned short* __restrict__ dst, float2* __restrict__ cgb) {
  int b = blockIdx.x;            // dst row 0..127
  int tid = threadIdx.x;         // 256 threads, 8 elems each
  int s = b >> 1;
  const float* src = (b & 1) ? wv : wk;
  int d0 = tid * 8;
  const f32x4* p = (const f32x4*)(src + (size_t)s * kD + d0);
  f32x4 v0 = p[0], v1 = p[1];
  f32x4 g0 = *(const f32x4*)&gamma[d0], g1 = *(const f32x4*)&gamma[d0 + 4];
  f32x4 b0 = *(const f32x4*)&beta[d0],  b1 = *(const f32x4*)&beta[d0 + 4];
  bfu8 o;
  float sg = 0.f, sb = 0.f;
#pragma unroll
  for (int j = 0; j < 4; ++j) {
    float gw0 = g0[j] * v0[j], gw1 = g1[j] * v1[j];
    o[j] = f2bf(gw0); o[j + 4] = f2bf(gw1);
    sg += gw0 + gw1;
    sb += b0[j] * v0[j] + b1[j] * v1[j];
  }
  *(bfu8*)(dst + (size_t)b * kD + d0) = o;
#pragma unroll
  for (int d = 1; d < 64; d <<= 1) { sg += __shfl_xor(sg, d); sb += __shfl_xor(sb, d); }
  __shared__ float gg[4], bb[4];
  if ((tid & 63) == 0) { gg[tid >> 6] = sg; bb[tid >> 6] = sb; }
  __syncthreads();
  if (tid == 0)
    cgb[b] = make_float2(gg[0] + gg[1] + gg[2] + gg[3], bb[0] + bb[1] + bb[2] + bb[3]);
}

// ---------------- 256x256 one-barrier-per-phase shift GEMM (R7/R12 known-good) ----------------
// x_shift = (roll(x) @ Wsh^T)*g + x*(1-g), written as bf16.
// Epilogue also emits per-(row, nblk) partial (sum, sumsq) for LN stats.
#define MM(x,y,z) __builtin_amdgcn_mfma_f32_16x16x32_bf16(x,y,z,0,0,0)
#define BAR __builtin_amdgcn_s_barrier()
#define WAITV_(N) asm volatile("s_waitcnt vmcnt(" #N ")" ::: "memory")
#define WAITV(N) WAITV_(N)
#define WAITL asm volatile("s_waitcnt lgkmcnt(0)")
#define NOWV (void)0

#define STAGEA_TO(BUF,H,Q,KT) gload16(aS + (size_t)(((H)*64+(Q)*128)*2048) + (KT), \
                                      smem + (BUF)*32768 + ((H)*64+(Q)*128)*64 + ldsAst)
#define STAGEB_TO(BUF,H,Q,KT) gload16(bS + (size_t)(((H)*32+(Q)*128)*2048) + (KT), \
                                      smem + (BUF)*32768 + 16384 + (H)*2048 + (Q)*8192 + ldsBst)

#define RDA(CUR,H,MF,KS) (*(const short8*)(smem + (CUR)*32768 + ardb + (H)*4096 + (MF)*1024 + colrd##KS))
#define RDB(CUR,H,NF,KS) (*(const short8*)(smem + (CUR)*32768 + 16384 + brdb + (H)*2048 + (NF)*1024 + colrd##KS))

#define RD_A(CUR,H) \
  a[0][0]=RDA(CUR,H,0,0); a[0][1]=RDA(CUR,H,0,1); \
  a[1][0]=RDA(CUR,H,1,0); a[1][1]=RDA(CUR,H,1,1); \
  a[2][0]=RDA(CUR,H,2,0); a[2][1]=RDA(CUR,H,2,1); \
  a[3][0]=RDA(CUR,H,3,0); a[3][1]=RDA(CUR,H,3,1)
#define RD_B(CUR,H,BV) \
  BV[0][0]=RDB(CUR,H,0,0); BV[0][1]=RDB(CUR,H,0,1); \
  BV[1][0]=RDB(CUR,H,1,0); BV[1][1]=RDB(CUR,H,1,1)

// k-outer MFMA order (same-acc distance 8); per-acc addend order k0,k1 preserved.
#define MF16(MH, B, NB) \
  __builtin_amdgcn_s_setprio(1); \
  acc[(MH)*4+0][(NB)+0] = MM(a[0][0], B[0][0], acc[(MH)*4+0][(NB)+0]); \
  acc[(MH)*4+0][(NB)+1] = MM(a[0][0], B[1][0], acc[(MH)*4+0][(NB)+1]); \
  acc[(MH)*4+1][(NB)+0] = MM(a[1][0], B[0][0], acc[(MH)*4+1][(NB)+0]); \
  acc[(MH)*4+1][(NB)+1] = MM(a[1][0], B[1][0], acc[(MH)*4+1][(NB)+1]); \
  acc[(MH)*4+2][(NB)+0] = MM(a[2][0], B[0][0], acc[(MH)*4+2][(NB)+0]); \
  acc[(MH)*4+2][(NB)+1] = MM(a[2][0], B[1][0], acc[(MH)*4+2][(NB)+1]); \
  acc[(MH)*4+3][(NB)+0] = MM(a[3][0], B[0][0], acc[(MH)*4+3][(NB)+0]); \
  acc[(MH)*4+3][(NB)+1] = MM(a[3][0], B[1][0], acc[(MH)*4+3][(NB)+1]); \
  acc[(MH)*4+0][(NB)+0] = MM(a[0][1], B[0][1], acc[(MH)*4+0][(NB)+0]); \
  acc[(MH)*4+0][(NB)+1] = MM(a[0][1], B[1][1], acc[(MH)*4+0][(NB)+1]); \
  acc[(MH)*4+1][(NB)+0] = MM(a[1][1], B[0][1], acc[(MH)*4+1][(NB)+0]); \
  acc[(MH)*4+1][(NB)+1] = MM(a[1][1], B[1][1], acc[(MH)*4+1][(NB)+1]); \
  acc[(MH)*4+2][(NB)+0] = MM(a[2][1], B[0][1], acc[(MH)*4+2][(NB)+0]); \
  acc[(MH)*4+2][(NB)+1] = MM(a[2][1], B[1][1], acc[(MH)*4+2][(NB)+1]); \
  acc[(MH)*4+3][(NB)+0] = MM(a[3][1], B[0][1], acc[(MH)*4+3][(NB)+0]); \
  acc[(MH)*4+3][(NB)+1] = MM(a[3][1], B[1][1], acc[(MH)*4+3][(NB)+1]); \
  __builtin_amdgcn_s_setprio(0)

// One-barrier bodies: [BAR; WAITL; MFMA(p); RD(p+1); STAGE; WAITV].
#define PH0(CUR, S, KA1, WV) \
  BAR; WAITL; MF16(0, b0, 0); \
  RD_B(CUR,1,b1); \
  if (S) { STAGEA_TO((CUR)^1, 1, 0, KA1); STAGEA_TO((CUR)^1, 1, 1, KA1); } \
  WV

#define PH1(CUR, S, KT2, WV) \
  BAR; WAITL; MF16(0, b1, 2); \
  RD_A(CUR,1); \
  if (S) { STAGEA_TO(CUR, 0, 0, KT2); STAGEA_TO(CUR, 0, 1, KT2); } \
  WV

#define PH2(CUR, S, KT2, WV) \
  BAR; WAITL; MF16(1, b0, 0); \
  if (S) { STAGEB_TO(CUR, 0, 0, KT2); STAGEB_TO(CUR, 0, 1, KT2); } \
  WV

#define PH3(CUR, RDN, S, KT2, WV) \
  BAR; WAITL; MF16(1, b1, 2); \
  if (RDN) { RD_A((CUR)^1,0); RD_B((CUR)^1,0,b0); } \
  if (S) { STAGEB_TO(CUR, 1, 0, KT2); STAGEB_TO(CUR, 1, 1, KT2); } \
  WV

__global__ __launch_bounds__(512, 2)
void k_gemm_shift8(const unsigned short* __restrict__ A,   // 16384x2048 bf16 x
                   const unsigned short* __restrict__ Bw,  // 2048x2048 bf16 W_shift
                   const float* __restrict__ gate,
                   unsigned short* __restrict__ out,       // x_shift bf16
                   float2* __restrict__ pstat) {           // per-(row, nblk) partial (sum, sumsq)
  __shared__ __align__(16) unsigned char smem_raw[131072];
  unsigned short* smem = (unsigned short*)smem_raw;

  const int tid = threadIdx.x;
  const int lane = tid & 63;
  const int w = tid >> 6;
  const int wr = w >> 2, wc = w & 3;
  const int lr = lane & 15, lq = lane >> 4;
  const int bid = blockIdx.x;
  const int nblk = bid & 7, mblk = bid >> 3;   // XCD keeps one N-panel L2-resident
  const int m0 = mblk * 256, n0 = nblk * 256;

  // staging addressing (pre-swizzled global source; linear LDS dest)
  const int r0 = tid >> 3;                                   // 0..63
  const int colel = ((tid & 7) * 8) ^ (((tid >> 3) & 7) << 3);
  const unsigned short* aS = A + (size_t)((m0 ^ 1024) + r0) * 2048 + colel;  // roll fused
  const unsigned short* bS = Bw + (size_t)(n0 + ((tid >> 8) << 6) + (r0 & 31)) * 2048 + colel;
  const int ldsAst = tid * 8;
  const int ldsBst = ((tid >> 8) << 12) + (tid & 255) * 8;

  // ds_read addressing (swizzled)
  const int ardb = (wr * 128 + lr) * 64;
  const int brdb = (wc * 64 + lr) * 64;
  const int colrd0 = (lq * 8) ^ ((lr & 7) << 3);
  const int colrd1 = (32 + lq * 8) ^ ((lr & 7) << 3);

  short8 a[4][2], b0[2][2], b1[2][2];
  f32x4 acc[8][4] = {};

  // prologue: tile0 (all 4 halves) then tile1's Ah0,Bh0,Bh1
  STAGEA_TO(0,0,0,0); STAGEA_TO(0,0,1,0);
  STAGEB_TO(0,0,0,0); STAGEB_TO(0,0,1,0);
  STAGEB_TO(0,1,0,0); STAGEB_TO(0,1,1,0);
  STAGEA_TO(0,1,0,0); STAGEA_TO(0,1,1,0);
  STAGEA_TO(1,0,0,64); STAGEA_TO(1,0,1,64);
  STAGEB_TO(1,0,0,64); STAGEB_TO(1,0,1,64);
  STAGEB_TO(1,1,0,64); STAGEB_TO(1,1,1,64);
  WAITV(6); BAR;
  RD_A(0,0); RD_B(0,0,b0);     // regs for tile0 P0

  int ka1 = 64, kt2 = 128;
  for (int j = 0; j < 15; ++j) {     // tiles 0..29
    PH0(0, 1, ka1, WAITV(8)); PH1(0, 1, kt2, WAITV(8));
    PH2(0, 1, kt2, WAITV(8)); PH3(0, 1, 1, kt2, WAITV(8));
    ka1 += 64; kt2 += 64;
    PH0(1, 1, ka1, WAITV(8)); PH1(1, 1, kt2, WAITV(8));
    PH2(1, 1, kt2, WAITV(8)); PH3(1, 1, 1, kt2, WAITV(8));
    ka1 += 64; kt2 += 64;
  }
  // tile 30 (CUR=0): stage only Ah1(31); tail waits
  PH0(0, 1, 1984, WAITV(8)); PH1(0, 0, 0, NOWV);
  PH2(0, 0, 0, WAITV(4));    PH3(0, 1, 0, 0, WAITV(2));
  // tile 31 (CUR=1): drain
  PH0(1, 0, 0, WAITV(0));    PH1(1, 0, 0, NOWV);
  PH2(1, 0, 0, NOWV);        PH3(1, 0, 0, 0, NOWV);

  // ---- epilogue: LDS transpose + fused sigmoid-gate blend, bf16 stores,
  //      + per-row partial LN stats (32 aligned lanes hold one row's 256 cols) ----
  float* cbuf = (float*)smem_raw;                 // 64 x 260 f32
#pragma unroll
  for (int q = 0; q < 4; ++q) {
    __syncthreads();
    if (wr == (q >> 1)) {
#pragma unroll
      for (int mm = 0; mm < 4; ++mm) {
#pragma unroll
        for (int nf = 0; nf < 4; ++nf) {
#pragma unroll
          for (int i = 0; i < 4; ++i) {
            int rl = mm * 16 + lq * 4 + i;
            int cl = wc * 64 + nf * 16 + lr;
            cbuf[rl * 260 + cl] = acc[(q & 1) * 4 + mm][nf][i];
          }
        }
      }
    }
    __syncthreads();
#pragma unroll
    for (int it = 0; it < 4; ++it) {
      int idx = tid + it * 512;
      int rl = idx >> 5, cb = (idx & 31) * 8;
      int gr = m0 + q * 64 + rl, gc = n0 + cb;
      f32x4 c0 = *(const f32x4*)&cbuf[rl * 260 + cb];
      f32x4 c1 = *(const f32x4*)&cbuf[rl * 260 + cb + 4];
      f32x4 g0 = *(const f32x4*)&gate[gc];
      f32x4 g1 = *(const f32x4*)&gate[gc + 4];
      bfu8 xv = *(const bfu8*)(A + (size_t)gr * 2048 + gc);
      bfu8 o;
      float ps = 0.f, pq = 0.f;
#pragma unroll
      for (int jj = 0; jj < 4; ++jj) {
        float g = 1.f / (1.f + __expf(-g0[jj]));
        o[jj] = f2bf(c0[jj] * g + bf2f(xv[jj]) * (1.f - g));
        float h = 1.f / (1.f + __expf(-g1[jj]));
        o[jj + 4] = f2bf(c1[jj] * h + bf2f(xv[jj + 4]) * (1.f - h));
        float f0 = bf2f(o[jj]), f1 = bf2f(o[jj + 4]);
        ps += f0 + f1;
        pq += f0 * f0 + f1 * f1;
      }
      *(bfu8*)(out + (size_t)gr * 2048 + gc) = o;
#pragma unroll
      for (int d = 1; d < 32; d <<= 1) { ps += __shfl_xor(ps, d); pq += __shfl_xor(pq, d); }
      if ((tid & 31) == 0) pstat[(size_t)gr * 8 + nblk] = make_float2(ps, pq);
    }
  }
}

// ---------------- finalize LN stats: fold 8 partials/row -> (mean, rstd) ----------------
__launch_bounds__(256)
__global__ void k_fin(const float2* __restrict__ pstat, float2* __restrict__ stats) {
  int m = blockIdx.x * 256 + threadIdx.x;
  const float2* p = pstat + (size_t)m * 8;
  float s = 0.f, q = 0.f;
#pragma unroll
  for (int i = 0; i < 8; ++i) { float2 v = p[i]; s += v.x; q += v.y; }
  float mean = s * (1.f / kD);
  float var = q * (1.f / kD) - mean * mean;
  stats[m] = make_float2(mean, rsqrtf(var + 1e-5f));
}

// ---------------- fused kv GEMM on x_shift with affine LN correction ----------------
__launch_bounds__(256, 2)
__global__ void k_gemm_kv_f(const unsigned short* __restrict__ A,     // x_shift bf16
                            const unsigned short* __restrict__ Bw,    // G = gamma*Wkv interleaved
                            const float2* __restrict__ stats,         // per-row (mu, rstd)
                            const float2* __restrict__ cgb,           // per-col (cg, cb)
                            const float* __restrict__ tfirst,
                            float* __restrict__ wkv) {
  __shared__ __align__(16) unsigned short As[32 * 32];
  __shared__ __align__(16) unsigned short Bs[128 * 32];
  __shared__ float2 rowst[32];
  const int tid = threadIdx.x;
  const int lane = tid & 63;
  const int wcv = tid >> 6;
  const int m0 = blockIdx.x * 32;
  const int lr = lane & 15, lk = (lane >> 4) << 3;
  const int c1 = tid, c2 = tid + 256;

  if (tid < 32) rowst[tid] = stats[m0 + tid];

  const unsigned short* ga = A + (size_t)(m0 + (tid >> 2)) * kD + ((tid & 3) << 3);
  const unsigned short* gb0 = Bw + (size_t)(c1 >> 2) * kD + ((c1 & 3) << 3);
  const unsigned short* gb1 = Bw + (size_t)(c2 >> 2) * kD + ((c2 & 3) << 3);
  unsigned short* la = As + tid * 8;
  unsigned short* lb0 = Bs + c1 * 8;
  unsigned short* lb1 = Bs + c2 * 8;

  f32x4 acc[2][2] = {};

  for (int kt = 0; kt < kD; kt += 32) {
    __syncthreads();
    if (tid < 128) gload16(ga + kt, la);
    gload16(gb0 + kt, lb0);
    gload16(gb1 + kt, lb1);
    __syncthreads();
    short8 af[2], bf[2];
#pragma unroll
    for (int mf = 0; mf < 2; ++mf)
      af[mf] = *(const short8*)&As[(mf * 16 + lr) * 32 + lk];
#pragma unroll
    for (int nf = 0; nf < 2; ++nf)
      bf[nf] = *(const short8*)&Bs[(wcv * 32 + nf * 16 + lr) * 32 + lk];
#pragma unroll
    for (int mf = 0; mf < 2; ++mf)
#pragma unroll
      for (int nf = 0; nf < 2; ++nf)
        acc[mf][nf] = __builtin_amdgcn_mfma_f32_16x16x32_bf16(af[mf], bf[nf], acc[mf][nf], 0, 0, 0);
  }

  const int fq = lane >> 4, fr = lane & 15;
#pragma unroll
  for (int mf = 0; mf < 2; ++mf) {
#pragma unroll
    for (int nf = 0; nf < 2; ++nf) {
      int c = wcv * 32 + nf * 16 + fr;
      float2 gc = cgb[c];
#pragma unroll
      for (int i = 0; i < 4; ++i) {
        int rloc = mf * 16 + fq * 4 + i;
        float2 st = rowst[rloc];
        float val = st.y * (acc[mf][nf][i] - st.x * gc.x) + gc.y;  // LN-corrected k or v
        float other = __shfl_xor(val, 1);
        if (!(c & 1)) {
          int s = c >> 1;
          float sk = 1.f / (1.f + expf(-val));
          float u = expf(tfirst[s]);
          wkv[(size_t)(m0 + rloc) * kDS + s] = expf(-u * sk) * other;
        }
      }
    }
  }
}

// ---------------- chunked linear scan (chunk=64, warmup 256) -> bf16 states ----------------
__global__ void k_scan(const float* __restrict__ wkv, const float* __restrict__ tdec,
                       unsigned short* __restrict__ states, float* __restrict__ last_state) {
  int chunk = blockIdx.x;   // 0..31
  int b = blockIdx.y;       // 0..7
  int s = threadIdx.x;      // 0..63
  float w = expf(tdec[s]);
  int t1 = chunk * 64;
  int warm = t1 < 256 ? t1 : 256;
  const float* base = wkv + (size_t)b * kNT * kDS + s;
  unsigned short* sbase = states + (size_t)b * kNT * kDS + s;
  float st = 0.f;
#pragma unroll 4
  for (int t = t1 - warm; t < t1; ++t) st = fmaf(st, w, base[(size_t)t * kDS]);
#pragma unroll 4
  for (int t = t1; t < t1 + 64; ++t) {
    st = fmaf(st, w, base[(size_t)t * kDS]);
    sbase[(size_t)t * kDS] = f2bf(st);
  }
  if (chunk == 31) last_state[b * kDS + s] = st;
}

// ---------------- output GEMM (bf16 MFMA, f32 out): 128x128 tiles, K=64 ----------------
__launch_bounds__(256, 3)
__global__ void k_out_gemm(const unsigned short* __restrict__ states,  // 16384x64 bf16
                           const unsigned short* __restrict__ Wo,      // 2048x64 bf16
                           float* __restrict__ out) {
  __shared__ __align__(16) unsigned char sraw[33792];
  unsigned short* As = (unsigned short*)sraw;          // 128*64 bf16 = 16384 B
  unsigned short* Bs = As + 8192;                      // 16384 B
  float* cbuf = (float*)sraw;                          // aliases As/Bs after fragment reads
  const int tid = threadIdx.x;
  const int lane = tid & 63;
  const int w = tid >> 6;
  const int wr = w >> 1, wc = w & 1;
  const int lr = lane & 15, lq = lane >> 4;
  const int n0 = blockIdx.x * 128;
  const int m0 = blockIdx.y * 128;

  const int sr0 = tid >> 3;
  const int scol = ((tid & 7) * 8) ^ (((tid >> 3) & 7) << 3);
#pragma unroll
  for (int rd = 0; rd < 4; ++rd) {
    gload16(states + (size_t)(m0 + sr0 + rd * 32) * 64 + scol, As + tid * 8 + rd * 2048);
    gload16(Wo + (size_t)(n0 + sr0 + rd * 32) * 64 + scol, Bs + tid * 8 + rd * 2048);
  }
  __syncthreads();

  short8 a[4][2], b[4][2];
#pragma unroll
  for (int mf = 0; mf < 4; ++mf) {
#pragma unroll
    for (int ks = 0; ks < 2; ++ks) {
      int col = (ks * 32 + lq * 8) ^ ((lr & 7) << 3);
      a[mf][ks] = *(const short8*)&As[(wr * 64 + mf * 16 + lr) * 64 + col];
      b[mf][ks] = *(const short8*)&Bs[(wc * 64 + mf * 16 + lr) * 64 + col];
    }
  }
  f32x4 acc[4][4] = {};
#pragma unroll
  for (int mf = 0; mf < 4; ++mf)
#pragma unroll
    for (int nf = 0; nf < 4; ++nf) {
      acc[mf][nf] = __builtin_amdgcn_mfma_f32_16x16x32_bf16(a[mf][0], b[nf][0], acc[mf][nf], 0, 0, 0);
      acc[mf][nf] = __builtin_amdgcn_mfma_f32_16x16x32_bf16(a[mf][1], b[nf][1], acc[mf][nf], 0, 0, 0);
    }

#pragma unroll
  for (int q = 0; q < 2; ++q) {
    __syncthreads();
    if (wr == q) {
#pragma unroll
      for (int mf = 0; mf < 4; ++mf)
#pragma unroll
        for (int nf = 0; nf < 4; ++nf)
#pragma unroll
          for (int i = 0; i < 4; ++i) {
            int rl = mf * 16 + lq * 4 + i;
            int cl = wc * 64 + nf * 16 + lr;
            cbuf[rl * 132 + cl] = acc[mf][nf][i];
          }
    }
    __syncthreads();
#pragma unroll
    for (int it = 0; it < 8; ++it) {
      int idx = tid + it * 256;
      int rl = idx >> 5, cb = (idx & 31) * 4;
      *(f32x4*)&out[(size_t)(m0 + q * 64 + rl) * kD + n0 + cb] = *(const f32x4*)&cbuf[rl * 132 + cb];
    }
  }
}

// ---------------- launcher ----------------
extern "C" void kernel_launch(void* const* d_in, const int* in_sizes, int n_in,
                              void* d_out, int out_size, void* d_ws, size_t ws_size,
                              hipStream_t stream) {
  const float* x    = (const float*)d_in[0];
  const float* Wk   = (const float*)d_in[1];
  const float* Wv   = (const float*)d_in[2];
  const float* Wo   = (const float*)d_in[3];
  const float* Wsh  = (const float*)d_in[4];
  const float* gate = (const float*)d_in[5];
  const float* tdec = (const float*)d_in[6];
  const float* tfir = (const float*)d_in[7];
  const float* lng  = (const float*)d_in[8];
  const float* lnb  = (const float*)d_in[9];
  float* out = (float*)d_out;
  char* ws = (char*)d_ws;

  unsigned short* xbf   = (unsigned short*)(ws);               // 67108864 B (x bf16)
  unsigned short* wshbf = (unsigned short*)(ws + 67108864);    //  8388608 B
  unsigned short* wkvbf = (unsigned short*)(ws + 75497472);    //   524288 B (G interleaved)
  float* wkvf           = (float*)(ws + 76021760);             //  4194304 B
  unsigned short* stbf  = (unsigned short*)(ws + 80216064);    //  2097152 B (states bf16)
  unsigned short* wobf  = (unsigned short*)(ws + 82313216);    //   262144 B (Wo bf16)
  float2* statsp        = (float2*)(ws + 82575360);            //   131072 B (mu, rstd per row)
  float2* cgbp          = (float2*)(ws + 82706432);            //     1024 B (cg, cb per col)
  float2* pstatp        = (float2*)(ws + 82707456);            //  1048576 B (partial sums)

  k_cvt<<<16384, 256, 0, stream>>>(x, xbf, 4194304);
  k_cvt<<<2048, 256, 0, stream>>>(Wsh, wshbf, 524288);
  k_cvt<<<64, 256, 0, stream>>>(Wo, wobf, 16384);
  k_cvt_kv_g<<<128, 256, 0, stream>>>(Wk, Wv, lng, lnb, wkvbf, cgbp);

  // x_shift (bf16) staged in d_out, overwritten later by the final output GEMM
  k_gemm_shift8<<<512, 512, 0, stream>>>(xbf, wshbf, gate, (unsigned short*)out, pstatp);
  k_fin<<<64, 256, 0, stream>>>(pstatp, statsp);
  k_gemm_kv_f<<<512, 256, 0, stream>>>((const unsigned short*)out, wkvbf, statsp, cgbp, tfir, wkvf);
  k_scan<<<dim3(32, 8), 64, 0, stream>>>(wkvf, tdec, stbf, out + kOutElems);
  k_out_gemm<<<dim3(16, 128), 256, 0, stream>>>(stbf, wobf, out);
}

// Round 16
// 275.741 us; speedup vs baseline: 1.0250x; 1.0024x over previous
//
#include <hip/hip_runtime.h>
#include <stdint.h>

// Problem constants
constexpr int kD  = 2048;   // D_ATTN
constexpr int kDS = 64;     // D_STATE
constexpr int kNT = 2048;   // T
constexpr int kM  = 8 * kNT;            // 16384 rows
constexpr int kOutElems = kM * kD;      // 33554432

typedef __attribute__((ext_vector_type(8))) short short8;
typedef __attribute__((ext_vector_type(8))) unsigned short bfu8;
typedef __attribute__((ext_vector_type(4))) float f32x4;

__device__ __forceinline__ unsigned short f2bf(float f) {
  unsigned int u = __float_as_uint(f);
  return (unsigned short)((u + 0x7FFFu + ((u >> 16) & 1u)) >> 16);
}
__device__ __forceinline__ float bf2f(unsigned short b) {
  return __uint_as_float(((unsigned int)b) << 16);
}

__device__ __forceinline__ void gload16(const void* g, void* l) {
  __builtin_amdgcn_global_load_lds((__attribute__((address_space(1))) void*)g,
                                   (__attribute__((address_space(3))) void*)l,
                                   16, 0, 0);
}

// ---------------- convert kernels ----------------
__global__ void k_cvt(const float* __restrict__ src, unsigned short* __restrict__ dst, int n8) {
  int i8 = blockIdx.x * 256 + threadIdx.x;
  if (i8 >= n8) return;
  const f32x4* s = (const f32x4*)(src + (size_t)i8 * 8);
  f32x4 v0 = s[0], v1 = s[1];
  bfu8 o;
  o[0] = f2bf(v0[0]); o[1] = f2bf(v0[1]); o[2] = f2bf(v0[2]); o[3] = f2bf(v0[3]);
  o[4] = f2bf(v1[0]); o[5] = f2bf(v1[1]); o[6] = f2bf(v1[2]); o[7] = f2bf(v1[3]);
  *(bfu8*)(dst + (size_t)i8 * 8) = o;
}

// Merged weight prep (one dispatch): blocks 0..2047 cvt W_shift; 2048..2111 cvt Wo;
// 2112..2239 build G = gamma*W_kv interleaved + per-row (cg, cb) scalars.
__launch_bounds__(256)
__global__ void k_cvt_w(const float* __restrict__ Wsh, const float* __restrict__ Wo,
                        const float* __restrict__ wk, const float* __restrict__ wv,
                        const float* __restrict__ gamma, const float* __restrict__ beta,
                        unsigned short* __restrict__ wshbf, unsigned short* __restrict__ wobf,
                        unsigned short* __restrict__ G, float2* __restrict__ cgb) {
  int blk = blockIdx.x;
  int tid = threadIdx.x;
  if (blk < 2048) {               // W_shift: 524288 chunks of 8
    int i8 = blk * 256 + tid;
    const f32x4* s = (const f32x4*)(Wsh + (size_t)i8 * 8);
    f32x4 v0 = s[0], v1 = s[1];
    bfu8 o;
    o[0] = f2bf(v0[0]); o[1] = f2bf(v0[1]); o[2] = f2bf(v0[2]); o[3] = f2bf(v0[3]);
    o[4] = f2bf(v1[0]); o[5] = f2bf(v1[1]); o[6] = f2bf(v1[2]); o[7] = f2bf(v1[3]);
    *(bfu8*)(wshbf + (size_t)i8 * 8) = o;
    return;
  }
  if (blk < 2112) {               // Wo: 16384 chunks of 8
    int i8 = (blk - 2048) * 256 + tid;
    const f32x4* s = (const f32x4*)(Wo + (size_t)i8 * 8);
    f32x4 v0 = s[0], v1 = s[1];
    bfu8 o;
    o[0] = f2bf(v0[0]); o[1] = f2bf(v0[1]); o[2] = f2bf(v0[2]); o[3] = f2bf(v0[3]);
    o[4] = f2bf(v1[0]); o[5] = f2bf(v1[1]); o[6] = f2bf(v1[2]); o[7] = f2bf(v1[3]);
    *(bfu8*)(wobf + (size_t)i8 * 8) = o;
    return;
  }
  // kv_g: 128 blocks, one interleaved G row each
  int b = blk - 2112;
  int s = b >> 1;
  const float* src = (b & 1) ? wv : wk;
  int d0 = tid * 8;
  const f32x4* p = (const f32x4*)(src + (size_t)s * kD + d0);
  f32x4 v0 = p[0], v1 = p[1];
  f32x4 g0 = *(const f32x4*)&gamma[d0], g1 = *(const f32x4*)&gamma[d0 + 4];
  f32x4 b0 = *(const f32x4*)&beta[d0],  b1 = *(const f32x4*)&beta[d0 + 4];
  bfu8 o;
  float sg = 0.f, sb = 0.f;
#pragma unroll
  for (int j = 0; j < 4; ++j) {
    float gw0 = g0[j] * v0[j], gw1 = g1[j] * v1[j];
    o[j] = f2bf(gw0); o[j + 4] = f2bf(gw1);
    sg += gw0 + gw1;
    sb += b0[j] * v0[j] + b1[j] * v1[j];
  }
  *(bfu8*)(G + (size_t)b * kD + d0) = o;
#pragma unroll
  for (int d = 1; d < 64; d <<= 1) { sg += __shfl_xor(sg, d); sb += __shfl_xor(sb, d); }
  __shared__ float gg[4], bb[4];
  if ((tid & 63) == 0) { gg[tid >> 6] = sg; bb[tid >> 6] = sb; }
  __syncthreads();
  if (tid == 0)
    cgb[b] = make_float2(gg[0] + gg[1] + gg[2] + gg[3], bb[0] + bb[1] + bb[2] + bb[3]);
}

// ---------------- 256x256 one-barrier-per-phase shift GEMM (R7/R12 known-good) ----------------
// x_shift = (roll(x) @ Wsh^T)*g + x*(1-g), written as bf16.
#define MM(x,y,z) __builtin_amdgcn_mfma_f32_16x16x32_bf16(x,y,z,0,0,0)
#define BAR __builtin_amdgcn_s_barrier()
#define WAITV_(N) asm volatile("s_waitcnt vmcnt(" #N ")" ::: "memory")
#define WAITV(N) WAITV_(N)
#define WAITL asm volatile("s_waitcnt lgkmcnt(0)")
#define NOWV (void)0

#define STAGEA_TO(BUF,H,Q,KT) gload16(aS + (size_t)(((H)*64+(Q)*128)*2048) + (KT), \
                                      smem + (BUF)*32768 + ((H)*64+(Q)*128)*64 + ldsAst)
#define STAGEB_TO(BUF,H,Q,KT) gload16(bS + (size_t)(((H)*32+(Q)*128)*2048) + (KT), \
                                      smem + (BUF)*32768 + 16384 + (H)*2048 + (Q)*8192 + ldsBst)

#define RDA(CUR,H,MF,KS) (*(const short8*)(smem + (CUR)*32768 + ardb + (H)*4096 + (MF)*1024 + colrd##KS))
#define RDB(CUR,H,NF,KS) (*(const short8*)(smem + (CUR)*32768 + 16384 + brdb + (H)*2048 + (NF)*1024 + colrd##KS))

#define RD_A(CUR,H) \
  a[0][0]=RDA(CUR,H,0,0); a[0][1]=RDA(CUR,H,0,1); \
  a[1][0]=RDA(CUR,H,1,0); a[1][1]=RDA(CUR,H,1,1); \
  a[2][0]=RDA(CUR,H,2,0); a[2][1]=RDA(CUR,H,2,1); \
  a[3][0]=RDA(CUR,H,3,0); a[3][1]=RDA(CUR,H,3,1)
#define RD_B(CUR,H,BV) \
  BV[0][0]=RDB(CUR,H,0,0); BV[0][1]=RDB(CUR,H,0,1); \
  BV[1][0]=RDB(CUR,H,1,0); BV[1][1]=RDB(CUR,H,1,1)

// k-outer MFMA order (same-acc distance 8); per-acc addend order k0,k1 preserved.
#define MF16(MH, B, NB) \
  __builtin_amdgcn_s_setprio(1); \
  acc[(MH)*4+0][(NB)+0] = MM(a[0][0], B[0][0], acc[(MH)*4+0][(NB)+0]); \
  acc[(MH)*4+0][(NB)+1] = MM(a[0][0], B[1][0], acc[(MH)*4+0][(NB)+1]); \
  acc[(MH)*4+1][(NB)+0] = MM(a[1][0], B[0][0], acc[(MH)*4+1][(NB)+0]); \
  acc[(MH)*4+1][(NB)+1] = MM(a[1][0], B[1][0], acc[(MH)*4+1][(NB)+1]); \
  acc[(MH)*4+2][(NB)+0] = MM(a[2][0], B[0][0], acc[(MH)*4+2][(NB)+0]); \
  acc[(MH)*4+2][(NB)+1] = MM(a[2][0], B[1][0], acc[(MH)*4+2][(NB)+1]); \
  acc[(MH)*4+3][(NB)+0] = MM(a[3][0], B[0][0], acc[(MH)*4+3][(NB)+0]); \
  acc[(MH)*4+3][(NB)+1] = MM(a[3][0], B[1][0], acc[(MH)*4+3][(NB)+1]); \
  acc[(MH)*4+0][(NB)+0] = MM(a[0][1], B[0][1], acc[(MH)*4+0][(NB)+0]); \
  acc[(MH)*4+0][(NB)+1] = MM(a[0][1], B[1][1], acc[(MH)*4+0][(NB)+1]); \
  acc[(MH)*4+1][(NB)+0] = MM(a[1][1], B[0][1], acc[(MH)*4+1][(NB)+0]); \
  acc[(MH)*4+1][(NB)+1] = MM(a[1][1], B[1][1], acc[(MH)*4+1][(NB)+1]); \
  acc[(MH)*4+2][(NB)+0] = MM(a[2][1], B[0][1], acc[(MH)*4+2][(NB)+0]); \
  acc[(MH)*4+2][(NB)+1] = MM(a[2][1], B[1][1], acc[(MH)*4+2][(NB)+1]); \
  acc[(MH)*4+3][(NB)+0] = MM(a[3][1], B[0][1], acc[(MH)*4+3][(NB)+0]); \
  acc[(MH)*4+3][(NB)+1] = MM(a[3][1], B[1][1], acc[(MH)*4+3][(NB)+1]); \
  __builtin_amdgcn_s_setprio(0)

// One-barrier bodies: [BAR; WAITL; MFMA(p); RD(p+1); STAGE; WAITV].
#define PH0(CUR, S, KA1, WV) \
  BAR; WAITL; MF16(0, b0, 0); \
  RD_B(CUR,1,b1); \
  if (S) { STAGEA_TO((CUR)^1, 1, 0, KA1); STAGEA_TO((CUR)^1, 1, 1, KA1); } \
  WV

#define PH1(CUR, S, KT2, WV) \
  BAR; WAITL; MF16(0, b1, 2); \
  RD_A(CUR,1); \
  if (S) { STAGEA_TO(CUR, 0, 0, KT2); STAGEA_TO(CUR, 0, 1, KT2); } \
  WV

#define PH2(CUR, S, KT2, WV) \
  BAR; WAITL; MF16(1, b0, 0); \
  if (S) { STAGEB_TO(CUR, 0, 0, KT2); STAGEB_TO(CUR, 0, 1, KT2); } \
  WV

#define PH3(CUR, RDN, S, KT2, WV) \
  BAR; WAITL; MF16(1, b1, 2); \
  if (RDN) { RD_A((CUR)^1,0); RD_B((CUR)^1,0,b0); } \
  if (S) { STAGEB_TO(CUR, 1, 0, KT2); STAGEB_TO(CUR, 1, 1, KT2); } \
  WV

__global__ __launch_bounds__(512, 2)
void k_gemm_shift8(const unsigned short* __restrict__ A,   // 16384x2048 bf16 x
                   const unsigned short* __restrict__ Bw,  // 2048x2048 bf16 W_shift
                   const float* __restrict__ gate,
                   unsigned short* __restrict__ out) {     // x_shift bf16
  __shared__ __align__(16) unsigned char smem_raw[131072];
  unsigned short* smem = (unsigned short*)smem_raw;

  const int tid = threadIdx.x;
  const int lane = tid & 63;
  const int w = tid >> 6;
  const int wr = w >> 2, wc = w & 3;
  const int lr = lane & 15, lq = lane >> 4;
  const int bid = blockIdx.x;
  const int nblk = bid & 7, mblk = bid >> 3;   // XCD keeps one N-panel L2-resident
  const int m0 = mblk * 256, n0 = nblk * 256;

  // staging addressing (pre-swizzled global source; linear LDS dest)
  const int r0 = tid >> 3;                                   // 0..63
  const int colel = ((tid & 7) * 8) ^ (((tid >> 3) & 7) << 3);
  const unsigned short* aS = A + (size_t)((m0 ^ 1024) + r0) * 2048 + colel;  // roll fused
  const unsigned short* bS = Bw + (size_t)(n0 + ((tid >> 8) << 6) + (r0 & 31)) * 2048 + colel;
  const int ldsAst = tid * 8;
  const int ldsBst = ((tid >> 8) << 12) + (tid & 255) * 8;

  // ds_read addressing (swizzled)
  const int ardb = (wr * 128 + lr) * 64;
  const int brdb = (wc * 64 + lr) * 64;
  const int colrd0 = (lq * 8) ^ ((lr & 7) << 3);
  const int colrd1 = (32 + lq * 8) ^ ((lr & 7) << 3);

  short8 a[4][2], b0[2][2], b1[2][2];
  f32x4 acc[8][4] = {};

  // prologue: tile0 (all 4 halves) then tile1's Ah0,Bh0,Bh1
  STAGEA_TO(0,0,0,0); STAGEA_TO(0,0,1,0);
  STAGEB_TO(0,0,0,0); STAGEB_TO(0,0,1,0);
  STAGEB_TO(0,1,0,0); STAGEB_TO(0,1,1,0);
  STAGEA_TO(0,1,0,0); STAGEA_TO(0,1,1,0);
  STAGEA_TO(1,0,0,64); STAGEA_TO(1,0,1,64);
  STAGEB_TO(1,0,0,64); STAGEB_TO(1,0,1,64);
  STAGEB_TO(1,1,0,64); STAGEB_TO(1,1,1,64);
  WAITV(6); BAR;
  RD_A(0,0); RD_B(0,0,b0);     // regs for tile0 P0

  int ka1 = 64, kt2 = 128;
  for (int j = 0; j < 15; ++j) {     // tiles 0..29
    PH0(0, 1, ka1, WAITV(8)); PH1(0, 1, kt2, WAITV(8));
    PH2(0, 1, kt2, WAITV(8)); PH3(0, 1, 1, kt2, WAITV(8));
    ka1 += 64; kt2 += 64;
    PH0(1, 1, ka1, WAITV(8)); PH1(1, 1, kt2, WAITV(8));
    PH2(1, 1, kt2, WAITV(8)); PH3(1, 1, 1, kt2, WAITV(8));
    ka1 += 64; kt2 += 64;
  }
  // tile 30 (CUR=0): stage only Ah1(31); tail waits
  PH0(0, 1, 1984, WAITV(8)); PH1(0, 0, 0, NOWV);
  PH2(0, 0, 0, WAITV(4));    PH3(0, 1, 0, 0, WAITV(2));
  // tile 31 (CUR=1): drain
  PH0(1, 0, 0, WAITV(0));    PH1(1, 0, 0, NOWV);
  PH2(1, 0, 0, NOWV);        PH3(1, 0, 0, 0, NOWV);

  // ---- epilogue: LDS transpose + fused sigmoid-gate blend, bf16 stores ----
  float* cbuf = (float*)smem_raw;                 // 64 x 260 f32
#pragma unroll
  for (int q = 0; q < 4; ++q) {
    __syncthreads();
    if (wr == (q >> 1)) {
#pragma unroll
      for (int mm = 0; mm < 4; ++mm) {
#pragma unroll
        for (int nf = 0; nf < 4; ++nf) {
#pragma unroll
          for (int i = 0; i < 4; ++i) {
            int rl = mm * 16 + lq * 4 + i;
            int cl = wc * 64 + nf * 16 + lr;
            cbuf[rl * 260 + cl] = acc[(q & 1) * 4 + mm][nf][i];
          }
        }
      }
    }
    __syncthreads();
#pragma unroll
    for (int it = 0; it < 4; ++it) {
      int idx = tid + it * 512;
      int rl = idx >> 5, cb = (idx & 31) * 8;
      int gr = m0 + q * 64 + rl, gc = n0 + cb;
      f32x4 c0 = *(const f32x4*)&cbuf[rl * 260 + cb];
      f32x4 c1 = *(const f32x4*)&cbuf[rl * 260 + cb + 4];
      f32x4 g0 = *(const f32x4*)&gate[gc];
      f32x4 g1 = *(const f32x4*)&gate[gc + 4];
      bfu8 xv = *(const bfu8*)(A + (size_t)gr * 2048 + gc);
      bfu8 o;
#pragma unroll
      for (int jj = 0; jj < 4; ++jj) {
        float g = 1.f / (1.f + __expf(-g0[jj]));
        o[jj] = f2bf(c0[jj] * g + bf2f(xv[jj]) * (1.f - g));
        float h = 1.f / (1.f + __expf(-g1[jj]));
        o[jj + 4] = f2bf(c1[jj] * h + bf2f(xv[jj + 4]) * (1.f - h));
      }
      *(bfu8*)(out + (size_t)gr * 2048 + gc) = o;
    }
  }
}

// ---------------- per-row LN stats from x_shift: (mean, rstd) ----------------
__launch_bounds__(256)
__global__ void k_stats(const unsigned short* __restrict__ xs, float2* __restrict__ stats) {
  int m = blockIdx.x;
  int tid = threadIdx.x;
  bfu8 v = *(const bfu8*)(xs + (size_t)m * kD + tid * 8);
  float s = 0.f, q = 0.f;
#pragma unroll
  for (int j = 0; j < 8; ++j) { float f = bf2f(v[j]); s += f; q += f * f; }
#pragma unroll
  for (int d = 1; d < 64; d <<= 1) { s += __shfl_xor(s, d); q += __shfl_xor(q, d); }
  __shared__ float ss[4], qq[4];
  if ((tid & 63) == 0) { ss[tid >> 6] = s; qq[tid >> 6] = q; }
  __syncthreads();
  if (tid == 0) {
    s = ss[0] + ss[1] + ss[2] + ss[3];
    q = qq[0] + qq[1] + qq[2] + qq[3];
    float mean = s * (1.f / kD);
    float var = q * (1.f / kD) - mean * mean;
    stats[m] = make_float2(mean, rsqrtf(var + 1e-5f));
  }
}

// ---------------- fused kv GEMM on x_shift with affine LN correction ----------------
__launch_bounds__(256, 2)
__global__ void k_gemm_kv_f(const unsigned short* __restrict__ A,     // x_shift bf16
                            const unsigned short* __restrict__ Bw,    // G = gamma*Wkv interleaved
                            const float2* __restrict__ stats,         // per-row (mu, rstd)
                            const float2* __restrict__ cgb,           // per-col (cg, cb)
                            const float* __restrict__ tfirst,
                            float* __restrict__ wkv) {
  __shared__ __align__(16) unsigned short As[32 * 32];
  __shared__ __align__(16) unsigned short Bs[128 * 32];
  __shared__ float2 rowst[32];
  const int tid = threadIdx.x;
  const int lane = tid & 63;
  const int wcv = tid >> 6;
  const int m0 = blockIdx.x * 32;
  const int lr = lane & 15, lk = (lane >> 4) << 3;
  const int c1 = tid, c2 = tid + 256;

  if (tid < 32) rowst[tid] = stats[m0 + tid];

  const unsigned short* ga = A + (size_t)(m0 + (tid >> 2)) * kD + ((tid & 3) << 3);
  const unsigned short* gb0 = Bw + (size_t)(c1 >> 2) * kD + ((c1 & 3) << 3);
  const unsigned short* gb1 = Bw + (size_t)(c2 >> 2) * kD + ((c2 & 3) << 3);
  unsigned short* la = As + tid * 8;
  unsigned short* lb0 = Bs + c1 * 8;
  unsigned short* lb1 = Bs + c2 * 8;

  f32x4 acc[2][2] = {};

  for (int kt = 0; kt < kD; kt += 32) {
    __syncthreads();
    if (tid < 128) gload16(ga + kt, la);
    gload16(gb0 + kt, lb0);
    gload16(gb1 + kt, lb1);
    __syncthreads();
    short8 af[2], bf[2];
#pragma unroll
    for (int mf = 0; mf < 2; ++mf)
      af[mf] = *(const short8*)&As[(mf * 16 + lr) * 32 + lk];
#pragma unroll
    for (int nf = 0; nf < 2; ++nf)
      bf[nf] = *(const short8*)&Bs[(wcv * 32 + nf * 16 + lr) * 32 + lk];
#pragma unroll
    for (int mf = 0; mf < 2; ++mf)
#pragma unroll
      for (int nf = 0; nf < 2; ++nf)
        acc[mf][nf] = __builtin_amdgcn_mfma_f32_16x16x32_bf16(af[mf], bf[nf], acc[mf][nf], 0, 0, 0);
  }

  const int fq = lane >> 4, fr = lane & 15;
#pragma unroll
  for (int mf = 0; mf < 2; ++mf) {
#pragma unroll
    for (int nf = 0; nf < 2; ++nf) {
      int c = wcv * 32 + nf * 16 + fr;
      float2 gc = cgb[c];
#pragma unroll
      for (int i = 0; i < 4; ++i) {
        int rloc = mf * 16 + fq * 4 + i;
        float2 st = rowst[rloc];
        float val = st.y * (acc[mf][nf][i] - st.x * gc.x) + gc.y;  // LN-corrected k or v
        float other = __shfl_xor(val, 1);
        if (!(c & 1)) {
          int s = c >> 1;
          float sk = 1.f / (1.f + expf(-val));
          float u = expf(tfirst[s]);
          wkv[(size_t)(m0 + rloc) * kDS + s] = expf(-u * sk) * other;
        }
      }
    }
  }
}

// ---------------- chunked linear scan (chunk=64, warmup 256) -> bf16 states ----------------
__global__ void k_scan(const float* __restrict__ wkv, const float* __restrict__ tdec,
                       unsigned short* __restrict__ states, float* __restrict__ last_state) {
  int chunk = blockIdx.x;   // 0..31
  int b = blockIdx.y;       // 0..7
  int s = threadIdx.x;      // 0..63
  float w = expf(tdec[s]);
  int t1 = chunk * 64;
  int warm = t1 < 256 ? t1 : 256;
  const float* base = wkv + (size_t)b * kNT * kDS + s;
  unsigned short* sbase = states + (size_t)b * kNT * kDS + s;
  float st = 0.f;
#pragma unroll 4
  for (int t = t1 - warm; t < t1; ++t) st = fmaf(st, w, base[(size_t)t * kDS]);
#pragma unroll 4
  for (int t = t1; t < t1 + 64; ++t) {
    st = fmaf(st, w, base[(size_t)t * kDS]);
    sbase[(size_t)t * kDS] = f2bf(st);
  }
  if (chunk == 31) last_state[b * kDS + s] = st;
}

// ---------------- output GEMM (bf16 MFMA, f32 out): 128x128 tiles, K=64 ----------------
__launch_bounds__(256, 3)
__global__ void k_out_gemm(const unsigned short* __restrict__ states,  // 16384x64 bf16
                           const unsigned short* __restrict__ Wo,      // 2048x64 bf16
                           float* __restrict__ out) {
  __shared__ __align__(16) unsigned char sraw[33792];
  unsigned short* As = (unsigned short*)sraw;          // 128*64 bf16 = 16384 B
  unsigned short* Bs = As + 8192;                      // 16384 B
  float* cbuf = (float*)sraw;                          // aliases As/Bs after fragment reads
  const int tid = threadIdx.x;
  const int lane = tid & 63;
  const int w = tid >> 6;
  const int wr = w >> 1, wc = w & 1;
  const int lr = lane & 15, lq = lane >> 4;
  const int n0 = blockIdx.x * 128;
  const int m0 = blockIdx.y * 128;

  const int sr0 = tid >> 3;
  const int scol = ((tid & 7) * 8) ^ (((tid >> 3) & 7) << 3);
#pragma unroll
  for (int rd = 0; rd < 4; ++rd) {
    gload16(states + (size_t)(m0 + sr0 + rd * 32) * 64 + scol, As + tid * 8 + rd * 2048);
    gload16(Wo + (size_t)(n0 + sr0 + rd * 32) * 64 + scol, Bs + tid * 8 + rd * 2048);
  }
  __syncthreads();

  short8 a[4][2], b[4][2];
#pragma unroll
  for (int mf = 0; mf < 4; ++mf) {
#pragma unroll
    for (int ks = 0; ks < 2; ++ks) {
      int col = (ks * 32 + lq * 8) ^ ((lr & 7) << 3);
      a[mf][ks] = *(const short8*)&As[(wr * 64 + mf * 16 + lr) * 64 + col];
      b[mf][ks] = *(const short8*)&Bs[(wc * 64 + mf * 16 + lr) * 64 + col];
    }
  }
  f32x4 acc[4][4] = {};
#pragma unroll
  for (int mf = 0; mf < 4; ++mf)
#pragma unroll
    for (int nf = 0; nf < 4; ++nf) {
      acc[mf][nf] = __builtin_amdgcn_mfma_f32_16x16x32_bf16(a[mf][0], b[nf][0], acc[mf][nf], 0, 0, 0);
      acc[mf][nf] = __builtin_amdgcn_mfma_f32_16x16x32_bf16(a[mf][1], b[nf][1], acc[mf][nf], 0, 0, 0);
    }

#pragma unroll
  for (int q = 0; q < 2; ++q) {
    __syncthreads();
    if (wr == q) {
#pragma unroll
      for (int mf = 0; mf < 4; ++mf)
#pragma unroll
        for (int nf = 0; nf < 4; ++nf)
#pragma unroll
          for (int i = 0; i < 4; ++i) {
            int rl = mf * 16 + lq * 4 + i;
            int cl = wc * 64 + nf * 16 + lr;
            cbuf[rl * 132 + cl] = acc[mf][nf][i];
          }
    }
    __syncthreads();
#pragma unroll
    for (int it = 0; it < 8; ++it) {
      int idx = tid + it * 256;
      int rl = idx >> 5, cb = (idx & 31) * 4;
      *(f32x4*)&out[(size_t)(m0 + q * 64 + rl) * kD + n0 + cb] = *(const f32x4*)&cbuf[rl * 132 + cb];
    }
  }
}

// ---------------- launcher ----------------
extern "C" void kernel_launch(void* const* d_in, const int* in_sizes, int n_in,
                              void* d_out, int out_size, void* d_ws, size_t ws_size,
                              hipStream_t stream) {
  const float* x    = (const float*)d_in[0];
  const float* Wk   = (const float*)d_in[1];
  const float* Wv   = (const float*)d_in[2];
  const float* Wo   = (const float*)d_in[3];
  const float* Wsh  = (const float*)d_in[4];
  const float* gate = (const float*)d_in[5];
  const float* tdec = (const float*)d_in[6];
  const float* tfir = (const float*)d_in[7];
  const float* lng  = (const float*)d_in[8];
  const float* lnb  = (const float*)d_in[9];
  float* out = (float*)d_out;
  char* ws = (char*)d_ws;

  unsigned short* xbf   = (unsigned short*)(ws);               // 67108864 B (x bf16)
  unsigned short* wshbf = (unsigned short*)(ws + 67108864);    //  8388608 B
  unsigned short* wkvbf = (unsigned short*)(ws + 75497472);    //   524288 B (G interleaved)
  float* wkvf           = (float*)(ws + 76021760);             //  4194304 B
  unsigned short* stbf  = (unsigned short*)(ws + 80216064);    //  2097152 B (states bf16)
  unsigned short* wobf  = (unsigned short*)(ws + 82313216);    //   262144 B (Wo bf16)
  float2* statsp        = (float2*)(ws + 82575360);            //   131072 B (mu, rstd per row)
  float2* cgbp          = (float2*)(ws + 82706432);            //     1024 B (cg, cb per col)

  k_cvt<<<16384, 256, 0, stream>>>(x, xbf, 4194304);
  k_cvt_w<<<2240, 256, 0, stream>>>(Wsh, Wo, Wk, Wv, lng, lnb, wshbf, wobf, wkvbf, cgbp);

  // x_shift (bf16) staged in d_out, overwritten later by the final output GEMM
  k_gemm_shift8<<<512, 512, 0, stream>>>(xbf, wshbf, gate, (unsigned short*)out);
  k_stats<<<16384, 256, 0, stream>>>((const unsigned short*)out, statsp);
  k_gemm_kv_f<<<512, 256, 0, stream>>>((const unsigned short*)out, wkvbf, statsp, cgbp, tfir, wkvf);
  k_scan<<<dim3(32, 8), 64, 0, stream>>>(wkvf, tdec, stbf, out + kOutElems);
  k_out_gemm<<<dim3(16, 128), 256, 0, stream>>>(stbf, wobf, out);
}

// Round 17
// 269.417 us; speedup vs baseline: 1.0491x; 1.0235x over previous
//
#include <hip/hip_runtime.h>
#include <stdint.h>

// Problem constants
constexpr int kD  = 2048;   // D_ATTN
constexpr int kDS = 64;     // D_STATE
constexpr int kNT = 2048;   // T
constexpr int kM  = 8 * kNT;            // 16384 rows
constexpr int kOutElems = kM * kD;      // 33554432

typedef __attribute__((ext_vector_type(8))) short short8;
typedef __attribute__((ext_vector_type(8))) unsigned short bfu8;
typedef __attribute__((ext_vector_type(4))) float f32x4;

__device__ __forceinline__ unsigned short f2bf(float f) {
  unsigned int u = __float_as_uint(f);
  return (unsigned short)((u + 0x7FFFu + ((u >> 16) & 1u)) >> 16);
}
__device__ __forceinline__ float bf2f(unsigned short b) {
  return __uint_as_float(((unsigned int)b) << 16);
}

__device__ __forceinline__ void gload16(const void* g, void* l) {
  __builtin_amdgcn_global_load_lds((__attribute__((address_space(1))) void*)g,
                                   (__attribute__((address_space(3))) void*)l,
                                   16, 0, 0);
}

// ---------------- convert kernels ----------------
__global__ void k_cvt(const float* __restrict__ src, unsigned short* __restrict__ dst, int n8) {
  int i8 = blockIdx.x * 256 + threadIdx.x;
  if (i8 >= n8) return;
  const f32x4* s = (const f32x4*)(src + (size_t)i8 * 8);
  f32x4 v0 = s[0], v1 = s[1];
  bfu8 o;
  o[0] = f2bf(v0[0]); o[1] = f2bf(v0[1]); o[2] = f2bf(v0[2]); o[3] = f2bf(v0[3]);
  o[4] = f2bf(v1[0]); o[5] = f2bf(v1[1]); o[6] = f2bf(v1[2]); o[7] = f2bf(v1[3]);
  *(bfu8*)(dst + (size_t)i8 * 8) = o;
}

// Merged weight prep (one dispatch): blocks 0..2047 cvt W_shift; 2048..2111 cvt Wo;
// 2112..2239 build G = gamma*W_kv interleaved + per-row (cg, cb) scalars.
__launch_bounds__(256)
__global__ void k_cvt_w(const float* __restrict__ Wsh, const float* __restrict__ Wo,
                        const float* __restrict__ wk, const float* __restrict__ wv,
                        const float* __restrict__ gamma, const float* __restrict__ beta,
                        unsigned short* __restrict__ wshbf, unsigned short* __restrict__ wobf,
                        unsigned short* __restrict__ G, float2* __restrict__ cgb) {
  int blk = blockIdx.x;
  int tid = threadIdx.x;
  if (blk < 2048) {               // W_shift: 524288 chunks of 8
    int i8 = blk * 256 + tid;
    const f32x4* s = (const f32x4*)(Wsh + (size_t)i8 * 8);
    f32x4 v0 = s[0], v1 = s[1];
    bfu8 o;
    o[0] = f2bf(v0[0]); o[1] = f2bf(v0[1]); o[2] = f2bf(v0[2]); o[3] = f2bf(v0[3]);
    o[4] = f2bf(v1[0]); o[5] = f2bf(v1[1]); o[6] = f2bf(v1[2]); o[7] = f2bf(v1[3]);
    *(bfu8*)(wshbf + (size_t)i8 * 8) = o;
    return;
  }
  if (blk < 2112) {               // Wo: 16384 chunks of 8
    int i8 = (blk - 2048) * 256 + tid;
    const f32x4* s = (const f32x4*)(Wo + (size_t)i8 * 8);
    f32x4 v0 = s[0], v1 = s[1];
    bfu8 o;
    o[0] = f2bf(v0[0]); o[1] = f2bf(v0[1]); o[2] = f2bf(v0[2]); o[3] = f2bf(v0[3]);
    o[4] = f2bf(v1[0]); o[5] = f2bf(v1[1]); o[6] = f2bf(v1[2]); o[7] = f2bf(v1[3]);
    *(bfu8*)(wobf + (size_t)i8 * 8) = o;
    return;
  }
  // kv_g: 128 blocks, one interleaved G row each
  int b = blk - 2112;
  int s = b >> 1;
  const float* src = (b & 1) ? wv : wk;
  int d0 = tid * 8;
  const f32x4* p = (const f32x4*)(src + (size_t)s * kD + d0);
  f32x4 v0 = p[0], v1 = p[1];
  f32x4 g0 = *(const f32x4*)&gamma[d0], g1 = *(const f32x4*)&gamma[d0 + 4];
  f32x4 b0 = *(const f32x4*)&beta[d0],  b1 = *(const f32x4*)&beta[d0 + 4];
  bfu8 o;
  float sg = 0.f, sb = 0.f;
#pragma unroll
  for (int j = 0; j < 4; ++j) {
    float gw0 = g0[j] * v0[j], gw1 = g1[j] * v1[j];
    o[j] = f2bf(gw0); o[j + 4] = f2bf(gw1);
    sg += gw0 + gw1;
    sb += b0[j] * v0[j] + b1[j] * v1[j];
  }
  *(bfu8*)(G + (size_t)b * kD + d0) = o;
#pragma unroll
  for (int d = 1; d < 64; d <<= 1) { sg += __shfl_xor(sg, d); sb += __shfl_xor(sb, d); }
  __shared__ float gg[4], bb[4];
  if ((tid & 63) == 0) { gg[tid >> 6] = sg; bb[tid >> 6] = sb; }
  __syncthreads();
  if (tid == 0)
    cgb[b] = make_float2(gg[0] + gg[1] + gg[2] + gg[3], bb[0] + bb[1] + bb[2] + bb[3]);
}

// ---------------- 256x256 one-barrier-per-phase shift GEMM (R7/R12 known-good) ----------------
// x_shift = (roll(x) @ Wsh^T)*g + x*(1-g), written as bf16.
#define MM(x,y,z) __builtin_amdgcn_mfma_f32_16x16x32_bf16(x,y,z,0,0,0)
#define BAR __builtin_amdgcn_s_barrier()
#define WAITV_(N) asm volatile("s_waitcnt vmcnt(" #N ")" ::: "memory")
#define WAITV(N) WAITV_(N)
#define WAITL asm volatile("s_waitcnt lgkmcnt(0)")
#define NOWV (void)0

#define STAGEA_TO(BUF,H,Q,KT) gload16(aS + (size_t)(((H)*64+(Q)*128)*2048) + (KT), \
                                      smem + (BUF)*32768 + ((H)*64+(Q)*128)*64 + ldsAst)
#define STAGEB_TO(BUF,H,Q,KT) gload16(bS + (size_t)(((H)*32+(Q)*128)*2048) + (KT), \
                                      smem + (BUF)*32768 + 16384 + (H)*2048 + (Q)*8192 + ldsBst)

#define RDA(CUR,H,MF,KS) (*(const short8*)(smem + (CUR)*32768 + ardb + (H)*4096 + (MF)*1024 + colrd##KS))
#define RDB(CUR,H,NF,KS) (*(const short8*)(smem + (CUR)*32768 + 16384 + brdb + (H)*2048 + (NF)*1024 + colrd##KS))

#define RD_A(CUR,H) \
  a[0][0]=RDA(CUR,H,0,0); a[0][1]=RDA(CUR,H,0,1); \
  a[1][0]=RDA(CUR,H,1,0); a[1][1]=RDA(CUR,H,1,1); \
  a[2][0]=RDA(CUR,H,2,0); a[2][1]=RDA(CUR,H,2,1); \
  a[3][0]=RDA(CUR,H,3,0); a[3][1]=RDA(CUR,H,3,1)
#define RD_B(CUR,H,BV) \
  BV[0][0]=RDB(CUR,H,0,0); BV[0][1]=RDB(CUR,H,0,1); \
  BV[1][0]=RDB(CUR,H,1,0); BV[1][1]=RDB(CUR,H,1,1)

// k-outer MFMA order (same-acc distance 8); per-acc addend order k0,k1 preserved.
#define MF16(MH, B, NB) \
  __builtin_amdgcn_s_setprio(1); \
  acc[(MH)*4+0][(NB)+0] = MM(a[0][0], B[0][0], acc[(MH)*4+0][(NB)+0]); \
  acc[(MH)*4+0][(NB)+1] = MM(a[0][0], B[1][0], acc[(MH)*4+0][(NB)+1]); \
  acc[(MH)*4+1][(NB)+0] = MM(a[1][0], B[0][0], acc[(MH)*4+1][(NB)+0]); \
  acc[(MH)*4+1][(NB)+1] = MM(a[1][0], B[1][0], acc[(MH)*4+1][(NB)+1]); \
  acc[(MH)*4+2][(NB)+0] = MM(a[2][0], B[0][0], acc[(MH)*4+2][(NB)+0]); \
  acc[(MH)*4+2][(NB)+1] = MM(a[2][0], B[1][0], acc[(MH)*4+2][(NB)+1]); \
  acc[(MH)*4+3][(NB)+0] = MM(a[3][0], B[0][0], acc[(MH)*4+3][(NB)+0]); \
  acc[(MH)*4+3][(NB)+1] = MM(a[3][0], B[1][0], acc[(MH)*4+3][(NB)+1]); \
  acc[(MH)*4+0][(NB)+0] = MM(a[0][1], B[0][1], acc[(MH)*4+0][(NB)+0]); \
  acc[(MH)*4+0][(NB)+1] = MM(a[0][1], B[1][1], acc[(MH)*4+0][(NB)+1]); \
  acc[(MH)*4+1][(NB)+0] = MM(a[1][1], B[0][1], acc[(MH)*4+1][(NB)+0]); \
  acc[(MH)*4+1][(NB)+1] = MM(a[1][1], B[1][1], acc[(MH)*4+1][(NB)+1]); \
  acc[(MH)*4+2][(NB)+0] = MM(a[2][1], B[0][1], acc[(MH)*4+2][(NB)+0]); \
  acc[(MH)*4+2][(NB)+1] = MM(a[2][1], B[1][1], acc[(MH)*4+2][(NB)+1]); \
  acc[(MH)*4+3][(NB)+0] = MM(a[3][1], B[0][1], acc[(MH)*4+3][(NB)+0]); \
  acc[(MH)*4+3][(NB)+1] = MM(a[3][1], B[1][1], acc[(MH)*4+3][(NB)+1]); \
  __builtin_amdgcn_s_setprio(0)

// One-barrier bodies: [BAR; WAITL; MFMA(p); RD(p+1); STAGE; WAITV].
#define PH0(CUR, S, KA1, WV) \
  BAR; WAITL; MF16(0, b0, 0); \
  RD_B(CUR,1,b1); \
  if (S) { STAGEA_TO((CUR)^1, 1, 0, KA1); STAGEA_TO((CUR)^1, 1, 1, KA1); } \
  WV

#define PH1(CUR, S, KT2, WV) \
  BAR; WAITL; MF16(0, b1, 2); \
  RD_A(CUR,1); \
  if (S) { STAGEA_TO(CUR, 0, 0, KT2); STAGEA_TO(CUR, 0, 1, KT2); } \
  WV

#define PH2(CUR, S, KT2, WV) \
  BAR; WAITL; MF16(1, b0, 0); \
  if (S) { STAGEB_TO(CUR, 0, 0, KT2); STAGEB_TO(CUR, 0, 1, KT2); } \
  WV

#define PH3(CUR, RDN, S, KT2, WV) \
  BAR; WAITL; MF16(1, b1, 2); \
  if (RDN) { RD_A((CUR)^1,0); RD_B((CUR)^1,0,b0); } \
  if (S) { STAGEB_TO(CUR, 1, 0, KT2); STAGEB_TO(CUR, 1, 1, KT2); } \
  WV

__global__ __launch_bounds__(512, 2)
void k_gemm_shift8(const unsigned short* __restrict__ A,   // 16384x2048 bf16 x
                   const unsigned short* __restrict__ Bw,  // 2048x2048 bf16 W_shift
                   const float* __restrict__ gate,
                   unsigned short* __restrict__ out) {     // x_shift bf16
  __shared__ __align__(16) unsigned char smem_raw[131072];
  unsigned short* smem = (unsigned short*)smem_raw;

  const int tid = threadIdx.x;
  const int lane = tid & 63;
  const int w = tid >> 6;
  const int wr = w >> 2, wc = w & 3;
  const int lr = lane & 15, lq = lane >> 4;
  const int bid = blockIdx.x;
  const int nblk = bid & 7, mblk = bid >> 3;   // XCD keeps one N-panel L2-resident
  const int m0 = mblk * 256, n0 = nblk * 256;

  // staging addressing (pre-swizzled global source; linear LDS dest)
  const int r0 = tid >> 3;                                   // 0..63
  const int colel = ((tid & 7) * 8) ^ (((tid >> 3) & 7) << 3);
  const unsigned short* aS = A + (size_t)((m0 ^ 1024) + r0) * 2048 + colel;  // roll fused
  const unsigned short* bS = Bw + (size_t)(n0 + ((tid >> 8) << 6) + (r0 & 31)) * 2048 + colel;
  const int ldsAst = tid * 8;
  const int ldsBst = ((tid >> 8) << 12) + (tid & 255) * 8;

  // ds_read addressing (swizzled)
  const int ardb = (wr * 128 + lr) * 64;
  const int brdb = (wc * 64 + lr) * 64;
  const int colrd0 = (lq * 8) ^ ((lr & 7) << 3);
  const int colrd1 = (32 + lq * 8) ^ ((lr & 7) << 3);

  short8 a[4][2], b0[2][2], b1[2][2];
  f32x4 acc[8][4] = {};

  // prologue: tile0 (all 4 halves) then tile1's Ah0,Bh0,Bh1
  STAGEA_TO(0,0,0,0); STAGEA_TO(0,0,1,0);
  STAGEB_TO(0,0,0,0); STAGEB_TO(0,0,1,0);
  STAGEB_TO(0,1,0,0); STAGEB_TO(0,1,1,0);
  STAGEA_TO(0,1,0,0); STAGEA_TO(0,1,1,0);
  STAGEA_TO(1,0,0,64); STAGEA_TO(1,0,1,64);
  STAGEB_TO(1,0,0,64); STAGEB_TO(1,0,1,64);
  STAGEB_TO(1,1,0,64); STAGEB_TO(1,1,1,64);
  WAITV(6); BAR;
  RD_A(0,0); RD_B(0,0,b0);     // regs for tile0 P0

  int ka1 = 64, kt2 = 128;
  for (int j = 0; j < 15; ++j) {     // tiles 0..29
    PH0(0, 1, ka1, WAITV(8)); PH1(0, 1, kt2, WAITV(8));
    PH2(0, 1, kt2, WAITV(8)); PH3(0, 1, 1, kt2, WAITV(8));
    ka1 += 64; kt2 += 64;
    PH0(1, 1, ka1, WAITV(8)); PH1(1, 1, kt2, WAITV(8));
    PH2(1, 1, kt2, WAITV(8)); PH3(1, 1, 1, kt2, WAITV(8));
    ka1 += 64; kt2 += 64;
  }
  // tile 30 (CUR=0): stage only Ah1(31); tail waits
  PH0(0, 1, 1984, WAITV(8)); PH1(0, 0, 0, NOWV);
  PH2(0, 0, 0, WAITV(4));    PH3(0, 1, 0, 0, WAITV(2));
  // tile 31 (CUR=1): drain
  PH0(1, 0, 0, WAITV(0));    PH1(1, 0, 0, NOWV);
  PH2(1, 0, 0, NOWV);        PH3(1, 0, 0, 0, NOWV);

  // ---- epilogue: LDS transpose + fused sigmoid-gate blend, bf16 stores ----
  float* cbuf = (float*)smem_raw;                 // 64 x 260 f32
#pragma unroll
  for (int q = 0; q < 4; ++q) {
    __syncthreads();
    if (wr == (q >> 1)) {
#pragma unroll
      for (int mm = 0; mm < 4; ++mm) {
#pragma unroll
        for (int nf = 0; nf < 4; ++nf) {
#pragma unroll
          for (int i = 0; i < 4; ++i) {
            int rl = mm * 16 + lq * 4 + i;
            int cl = wc * 64 + nf * 16 + lr;
            cbuf[rl * 260 + cl] = acc[(q & 1) * 4 + mm][nf][i];
          }
        }
      }
    }
    __syncthreads();
#pragma unroll
    for (int it = 0; it < 4; ++it) {
      int idx = tid + it * 512;
      int rl = idx >> 5, cb = (idx & 31) * 8;
      int gr = m0 + q * 64 + rl, gc = n0 + cb;
      f32x4 c0 = *(const f32x4*)&cbuf[rl * 260 + cb];
      f32x4 c1 = *(const f32x4*)&cbuf[rl * 260 + cb + 4];
      f32x4 g0 = *(const f32x4*)&gate[gc];
      f32x4 g1 = *(const f32x4*)&gate[gc + 4];
      bfu8 xv = *(const bfu8*)(A + (size_t)gr * 2048 + gc);
      bfu8 o;
#pragma unroll
      for (int jj = 0; jj < 4; ++jj) {
        float g = 1.f / (1.f + __expf(-g0[jj]));
        o[jj] = f2bf(c0[jj] * g + bf2f(xv[jj]) * (1.f - g));
        float h = 1.f / (1.f + __expf(-g1[jj]));
        o[jj + 4] = f2bf(c1[jj] * h + bf2f(xv[jj + 4]) * (1.f - h));
      }
      *(bfu8*)(out + (size_t)gr * 2048 + gc) = o;
    }
  }
}

// ---------------- fused LN-stats + kv GEMM on x_shift with affine LN correction ----------------
// Prologue: per-block 32-row (mu, rstd) into LDS (single HBM read; GEMM A-loads hit L2).
// GEMM loop and epilogue identical to R13 (no per-K-tile LN work).
__launch_bounds__(256, 2)
__global__ void k_gemm_kv_f(const unsigned short* __restrict__ A,     // x_shift bf16
                            const unsigned short* __restrict__ Bw,    // G = gamma*Wkv interleaved
                            const float2* __restrict__ cgb,           // per-col (cg, cb)
                            const float* __restrict__ tfirst,
                            float* __restrict__ wkv) {
  __shared__ __align__(16) unsigned short As[32 * 32];
  __shared__ __align__(16) unsigned short Bs[128 * 32];
  __shared__ float2 rowst[32];
  const int tid = threadIdx.x;
  const int lane = tid & 63;
  const int wcv = tid >> 6;
  const int m0 = blockIdx.x * 32;
  const int lr = lane & 15, lk = (lane >> 4) << 3;
  const int c1 = tid, c2 = tid + 256;

  // ---- prologue: per-row mean/var (8 lanes per row, shfl reduce) ----
  {
    int r = tid >> 3, c8 = tid & 7;
    const unsigned short* row = A + (size_t)(m0 + r) * kD;
    float s = 0.f, q = 0.f;
#pragma unroll 4
    for (int i = 0; i < 32; ++i) {
      bfu8 v = *(const bfu8*)(row + (c8 + i * 8) * 8);
#pragma unroll
      for (int j = 0; j < 8; ++j) { float f = bf2f(v[j]); s += f; q += f * f; }
    }
    s += __shfl_xor(s, 1); q += __shfl_xor(q, 1);
    s += __shfl_xor(s, 2); q += __shfl_xor(q, 2);
    s += __shfl_xor(s, 4); q += __shfl_xor(q, 4);
    if (c8 == 0) {
      float mu = s * (1.f / kD);
      float var = q * (1.f / kD) - mu * mu;
      rowst[r] = make_float2(mu, rsqrtf(var + 1e-5f));
    }
  }

  const unsigned short* ga = A + (size_t)(m0 + (tid >> 2)) * kD + ((tid & 3) << 3);
  const unsigned short* gb0 = Bw + (size_t)(c1 >> 2) * kD + ((c1 & 3) << 3);
  const unsigned short* gb1 = Bw + (size_t)(c2 >> 2) * kD + ((c2 & 3) << 3);
  unsigned short* la = As + tid * 8;
  unsigned short* lb0 = Bs + c1 * 8;
  unsigned short* lb1 = Bs + c2 * 8;

  f32x4 acc[2][2] = {};

  for (int kt = 0; kt < kD; kt += 32) {
    __syncthreads();
    if (tid < 128) gload16(ga + kt, la);
    gload16(gb0 + kt, lb0);
    gload16(gb1 + kt, lb1);
    __syncthreads();
    short8 af[2], bf[2];
#pragma unroll
    for (int mf = 0; mf < 2; ++mf)
      af[mf] = *(const short8*)&As[(mf * 16 + lr) * 32 + lk];
#pragma unroll
    for (int nf = 0; nf < 2; ++nf)
      bf[nf] = *(const short8*)&Bs[(wcv * 32 + nf * 16 + lr) * 32 + lk];
#pragma unroll
    for (int mf = 0; mf < 2; ++mf)
#pragma unroll
      for (int nf = 0; nf < 2; ++nf)
        acc[mf][nf] = __builtin_amdgcn_mfma_f32_16x16x32_bf16(af[mf], bf[nf], acc[mf][nf], 0, 0, 0);
  }

  const int fq = lane >> 4, fr = lane & 15;
#pragma unroll
  for (int mf = 0; mf < 2; ++mf) {
#pragma unroll
    for (int nf = 0; nf < 2; ++nf) {
      int c = wcv * 32 + nf * 16 + fr;
      float2 gc = cgb[c];
#pragma unroll
      for (int i = 0; i < 4; ++i) {
        int rloc = mf * 16 + fq * 4 + i;
        float2 st = rowst[rloc];
        float val = st.y * (acc[mf][nf][i] - st.x * gc.x) + gc.y;  // LN-corrected k or v
        float other = __shfl_xor(val, 1);
        if (!(c & 1)) {
          int s = c >> 1;
          float sk = 1.f / (1.f + expf(-val));
          float u = expf(tfirst[s]);
          wkv[(size_t)(m0 + rloc) * kDS + s] = expf(-u * sk) * other;
        }
      }
    }
  }
}

// ---------------- chunked linear scan (chunk=64, warmup 256) -> bf16 states ----------------
__global__ void k_scan(const float* __restrict__ wkv, const float* __restrict__ tdec,
                       unsigned short* __restrict__ states, float* __restrict__ last_state) {
  int chunk = blockIdx.x;   // 0..31
  int b = blockIdx.y;       // 0..7
  int s = threadIdx.x;      // 0..63
  float w = expf(tdec[s]);
  int t1 = chunk * 64;
  int warm = t1 < 256 ? t1 : 256;
  const float* base = wkv + (size_t)b * kNT * kDS + s;
  unsigned short* sbase = states + (size_t)b * kNT * kDS + s;
  float st = 0.f;
#pragma unroll 4
  for (int t = t1 - warm; t < t1; ++t) st = fmaf(st, w, base[(size_t)t * kDS]);
#pragma unroll 4
  for (int t = t1; t < t1 + 64; ++t) {
    st = fmaf(st, w, base[(size_t)t * kDS]);
    sbase[(size_t)t * kDS] = f2bf(st);
  }
  if (chunk == 31) last_state[b * kDS + s] = st;
}

// ---------------- output GEMM (bf16 MFMA, f32 out): 128x128 tiles, K=64 ----------------
__launch_bounds__(256, 3)
__global__ void k_out_gemm(const unsigned short* __restrict__ states,  // 16384x64 bf16
                           const unsigned short* __restrict__ Wo,      // 2048x64 bf16
                           float* __restrict__ out) {
  __shared__ __align__(16) unsigned char sraw[33792];
  unsigned short* As = (unsigned short*)sraw;          // 128*64 bf16 = 16384 B
  unsigned short* Bs = As + 8192;                      // 16384 B
  float* cbuf = (float*)sraw;                          // aliases As/Bs after fragment reads
  const int tid = threadIdx.x;
  const int lane = tid & 63;
  const int w = tid >> 6;
  const int wr = w >> 1, wc = w & 1;
  const int lr = lane & 15, lq = lane >> 4;
  const int n0 = blockIdx.x * 128;
  const int m0 = blockIdx.y * 128;

  const int sr0 = tid >> 3;
  const int scol = ((tid & 7) * 8) ^ (((tid >> 3) & 7) << 3);
#pragma unroll
  for (int rd = 0; rd < 4; ++rd) {
    gload16(states + (size_t)(m0 + sr0 + rd * 32) * 64 + scol, As + tid * 8 + rd * 2048);
    gload16(Wo + (size_t)(n0 + sr0 + rd * 32) * 64 + scol, Bs + tid * 8 + rd * 2048);
  }
  __syncthreads();

  short8 a[4][2], b[4][2];
#pragma unroll
  for (int mf = 0; mf < 4; ++mf) {
#pragma unroll
    for (int ks = 0; ks < 2; ++ks) {
      int col = (ks * 32 + lq * 8) ^ ((lr & 7) << 3);
      a[mf][ks] = *(const short8*)&As[(wr * 64 + mf * 16 + lr) * 64 + col];
      b[mf][ks] = *(const short8*)&Bs[(wc * 64 + mf * 16 + lr) * 64 + col];
    }
  }
  f32x4 acc[4][4] = {};
#pragma unroll
  for (int mf = 0; mf < 4; ++mf)
#pragma unroll
    for (int nf = 0; nf < 4; ++nf) {
      acc[mf][nf] = __builtin_amdgcn_mfma_f32_16x16x32_bf16(a[mf][0], b[nf][0], acc[mf][nf], 0, 0, 0);
      acc[mf][nf] = __builtin_amdgcn_mfma_f32_16x16x32_bf16(a[mf][1], b[nf][1], acc[mf][nf], 0, 0, 0);
    }

#pragma unroll
  for (int q = 0; q < 2; ++q) {
    __syncthreads();
    if (wr == q) {
#pragma unroll
      for (int mf = 0; mf < 4; ++mf)
#pragma unroll
        for (int nf = 0; nf < 4; ++nf)
#pragma unroll
          for (int i = 0; i < 4; ++i) {
            int rl = mf * 16 + lq * 4 + i;
            int cl = wc * 64 + nf * 16 + lr;
            cbuf[rl * 132 + cl] = acc[mf][nf][i];
          }
    }
    __syncthreads();
#pragma unroll
    for (int it = 0; it < 8; ++it) {
      int idx = tid + it * 256;
      int rl = idx >> 5, cb = (idx & 31) * 4;
      *(f32x4*)&out[(size_t)(m0 + q * 64 + rl) * kD + n0 + cb] = *(const f32x4*)&cbuf[rl * 132 + cb];
    }
  }
}

// ---------------- launcher ----------------
extern "C" void kernel_launch(void* const* d_in, const int* in_sizes, int n_in,
                              void* d_out, int out_size, void* d_ws, size_t ws_size,
                              hipStream_t stream) {
  const float* x    = (const float*)d_in[0];
  const float* Wk   = (const float*)d_in[1];
  const float* Wv   = (const float*)d_in[2];
  const float* Wo   = (const float*)d_in[3];
  const float* Wsh  = (const float*)d_in[4];
  const float* gate = (const float*)d_in[5];
  const float* tdec = (const float*)d_in[6];
  const float* tfir = (const float*)d_in[7];
  const float* lng  = (const float*)d_in[8];
  const float* lnb  = (const float*)d_in[9];
  float* out = (float*)d_out;
  char* ws = (char*)d_ws;

  unsigned short* xbf   = (unsigned short*)(ws);               // 67108864 B (x bf16)
  unsigned short* wshbf = (unsigned short*)(ws + 67108864);    //  8388608 B
  unsigned short* wkvbf = (unsigned short*)(ws + 75497472);    //   524288 B (G interleaved)
  float* wkvf           = (float*)(ws + 76021760);             //  4194304 B
  unsigned short* stbf  = (unsigned short*)(ws + 80216064);    //  2097152 B (states bf16)
  unsigned short* wobf  = (unsigned short*)(ws + 82313216);    //   262144 B (Wo bf16)
  float2* cgbp          = (float2*)(ws + 82575360);            //     1024 B (cg, cb per col)

  k_cvt<<<16384, 256, 0, stream>>>(x, xbf, 4194304);
  k_cvt_w<<<2240, 256, 0, stream>>>(Wsh, Wo, Wk, Wv, lng, lnb, wshbf, wobf, wkvbf, cgbp);

  // x_shift (bf16) staged in d_out, overwritten later by the final output GEMM
  k_gemm_shift8<<<512, 512, 0, stream>>>(xbf, wshbf, gate, (unsigned short*)out);
  k_gemm_kv_f<<<512, 256, 0, stream>>>((const unsigned short*)out, wkvbf, cgbp, tfir, wkvf);
  k_scan<<<dim3(32, 8), 64, 0, stream>>>(wkvf, tdec, stbf, out + kOutElems);
  k_out_gemm<<<dim3(16, 128), 256, 0, stream>>>(stbf, wobf, out);
}

// Round 18
// 266.625 us; speedup vs baseline: 1.0601x; 1.0105x over previous
//
#include <hip/hip_runtime.h>
#include <stdint.h>

// Problem constants
constexpr int kD  = 2048;   // D_ATTN
constexpr int kDS = 64;     // D_STATE
constexpr int kNT = 2048;   // T
constexpr int kM  = 8 * kNT;            // 16384 rows
constexpr int kOutElems = kM * kD;      // 33554432

typedef __attribute__((ext_vector_type(8))) short short8;
typedef __attribute__((ext_vector_type(8))) unsigned short bfu8;
typedef __attribute__((ext_vector_type(4))) float f32x4;

__device__ __forceinline__ unsigned short f2bf(float f) {
  unsigned int u = __float_as_uint(f);
  return (unsigned short)((u + 0x7FFFu + ((u >> 16) & 1u)) >> 16);
}
__device__ __forceinline__ float bf2f(unsigned short b) {
  return __uint_as_float(((unsigned int)b) << 16);
}

__device__ __forceinline__ void gload16(const void* g, void* l) {
  __builtin_amdgcn_global_load_lds((__attribute__((address_space(1))) void*)g,
                                   (__attribute__((address_space(3))) void*)l,
                                   16, 0, 0);
}

// ---------------- merged prep (one dispatch) ----------------
// blocks 0..16383: cvt x -> bf16; 16384..18431: cvt W_shift; 18432..18495: cvt Wo;
// 18496..18623: G = gamma*W_kv interleaved + per-row (cg, cb).
__launch_bounds__(256)
__global__ void k_prep(const float* __restrict__ x, const float* __restrict__ Wsh,
                       const float* __restrict__ Wo,
                       const float* __restrict__ wk, const float* __restrict__ wv,
                       const float* __restrict__ gamma, const float* __restrict__ beta,
                       unsigned short* __restrict__ xbf, unsigned short* __restrict__ wshbf,
                       unsigned short* __restrict__ wobf,
                       unsigned short* __restrict__ G, float2* __restrict__ cgb) {
  int blk = blockIdx.x;
  int tid = threadIdx.x;
  if (blk < 16384) {              // x: 4194304 chunks of 8
    int i8 = blk * 256 + tid;
    const f32x4* s = (const f32x4*)(x + (size_t)i8 * 8);
    f32x4 v0 = s[0], v1 = s[1];
    bfu8 o;
    o[0] = f2bf(v0[0]); o[1] = f2bf(v0[1]); o[2] = f2bf(v0[2]); o[3] = f2bf(v0[3]);
    o[4] = f2bf(v1[0]); o[5] = f2bf(v1[1]); o[6] = f2bf(v1[2]); o[7] = f2bf(v1[3]);
    *(bfu8*)(xbf + (size_t)i8 * 8) = o;
    return;
  }
  if (blk < 18432) {              // W_shift: 524288 chunks of 8
    int i8 = (blk - 16384) * 256 + tid;
    const f32x4* s = (const f32x4*)(Wsh + (size_t)i8 * 8);
    f32x4 v0 = s[0], v1 = s[1];
    bfu8 o;
    o[0] = f2bf(v0[0]); o[1] = f2bf(v0[1]); o[2] = f2bf(v0[2]); o[3] = f2bf(v0[3]);
    o[4] = f2bf(v1[0]); o[5] = f2bf(v1[1]); o[6] = f2bf(v1[2]); o[7] = f2bf(v1[3]);
    *(bfu8*)(wshbf + (size_t)i8 * 8) = o;
    return;
  }
  if (blk < 18496) {              // Wo: 16384 chunks of 8
    int i8 = (blk - 18432) * 256 + tid;
    const f32x4* s = (const f32x4*)(Wo + (size_t)i8 * 8);
    f32x4 v0 = s[0], v1 = s[1];
    bfu8 o;
    o[0] = f2bf(v0[0]); o[1] = f2bf(v0[1]); o[2] = f2bf(v0[2]); o[3] = f2bf(v0[3]);
    o[4] = f2bf(v1[0]); o[5] = f2bf(v1[1]); o[6] = f2bf(v1[2]); o[7] = f2bf(v1[3]);
    *(bfu8*)(wobf + (size_t)i8 * 8) = o;
    return;
  }
  // kv_g: 128 blocks, one interleaved G row each
  int b = blk - 18496;
  int s = b >> 1;
  const float* src = (b & 1) ? wv : wk;
  int d0 = tid * 8;
  const f32x4* p = (const f32x4*)(src + (size_t)s * kD + d0);
  f32x4 v0 = p[0], v1 = p[1];
  f32x4 g0 = *(const f32x4*)&gamma[d0], g1 = *(const f32x4*)&gamma[d0 + 4];
  f32x4 b0 = *(const f32x4*)&beta[d0],  b1 = *(const f32x4*)&beta[d0 + 4];
  bfu8 o;
  float sg = 0.f, sb = 0.f;
#pragma unroll
  for (int j = 0; j < 4; ++j) {
    float gw0 = g0[j] * v0[j], gw1 = g1[j] * v1[j];
    o[j] = f2bf(gw0); o[j + 4] = f2bf(gw1);
    sg += gw0 + gw1;
    sb += b0[j] * v0[j] + b1[j] * v1[j];
  }
  *(bfu8*)(G + (size_t)b * kD + d0) = o;
#pragma unroll
  for (int d = 1; d < 64; d <<= 1) { sg += __shfl_xor(sg, d); sb += __shfl_xor(sb, d); }
  __shared__ float gg[4], bb[4];
  if ((tid & 63) == 0) { gg[tid >> 6] = sg; bb[tid >> 6] = sb; }
  __syncthreads();
  if (tid == 0)
    cgb[b] = make_float2(gg[0] + gg[1] + gg[2] + gg[3], bb[0] + bb[1] + bb[2] + bb[3]);
}

// ---------------- 256x256 one-barrier-per-phase shift GEMM (R7/R12 known-good) ----------------
// x_shift = (roll(x) @ Wsh^T)*g + x*(1-g), written as bf16.
#define MM(x,y,z) __builtin_amdgcn_mfma_f32_16x16x32_bf16(x,y,z,0,0,0)
#define BAR __builtin_amdgcn_s_barrier()
#define WAITV_(N) asm volatile("s_waitcnt vmcnt(" #N ")" ::: "memory")
#define WAITV(N) WAITV_(N)
#define WAITL asm volatile("s_waitcnt lgkmcnt(0)")
#define NOWV (void)0

#define STAGEA_TO(BUF,H,Q,KT) gload16(aS + (size_t)(((H)*64+(Q)*128)*2048) + (KT), \
                                      smem + (BUF)*32768 + ((H)*64+(Q)*128)*64 + ldsAst)
#define STAGEB_TO(BUF,H,Q,KT) gload16(bS + (size_t)(((H)*32+(Q)*128)*2048) + (KT), \
                                      smem + (BUF)*32768 + 16384 + (H)*2048 + (Q)*8192 + ldsBst)

#define RDA(CUR,H,MF,KS) (*(const short8*)(smem + (CUR)*32768 + ardb + (H)*4096 + (MF)*1024 + colrd##KS))
#define RDB(CUR,H,NF,KS) (*(const short8*)(smem + (CUR)*32768 + 16384 + brdb + (H)*2048 + (NF)*1024 + colrd##KS))

#define RD_A(CUR,H) \
  a[0][0]=RDA(CUR,H,0,0); a[0][1]=RDA(CUR,H,0,1); \
  a[1][0]=RDA(CUR,H,1,0); a[1][1]=RDA(CUR,H,1,1); \
  a[2][0]=RDA(CUR,H,2,0); a[2][1]=RDA(CUR,H,2,1); \
  a[3][0]=RDA(CUR,H,3,0); a[3][1]=RDA(CUR,H,3,1)
#define RD_B(CUR,H,BV) \
  BV[0][0]=RDB(CUR,H,0,0); BV[0][1]=RDB(CUR,H,0,1); \
  BV[1][0]=RDB(CUR,H,1,0); BV[1][1]=RDB(CUR,H,1,1)

// k-outer MFMA order (same-acc distance 8); per-acc addend order k0,k1 preserved.
#define MF16(MH, B, NB) \
  __builtin_amdgcn_s_setprio(1); \
  acc[(MH)*4+0][(NB)+0] = MM(a[0][0], B[0][0], acc[(MH)*4+0][(NB)+0]); \
  acc[(MH)*4+0][(NB)+1] = MM(a[0][0], B[1][0], acc[(MH)*4+0][(NB)+1]); \
  acc[(MH)*4+1][(NB)+0] = MM(a[1][0], B[0][0], acc[(MH)*4+1][(NB)+0]); \
  acc[(MH)*4+1][(NB)+1] = MM(a[1][0], B[1][0], acc[(MH)*4+1][(NB)+1]); \
  acc[(MH)*4+2][(NB)+0] = MM(a[2][0], B[0][0], acc[(MH)*4+2][(NB)+0]); \
  acc[(MH)*4+2][(NB)+1] = MM(a[2][0], B[1][0], acc[(MH)*4+2][(NB)+1]); \
  acc[(MH)*4+3][(NB)+0] = MM(a[3][0], B[0][0], acc[(MH)*4+3][(NB)+0]); \
  acc[(MH)*4+3][(NB)+1] = MM(a[3][0], B[1][0], acc[(MH)*4+3][(NB)+1]); \
  acc[(MH)*4+0][(NB)+0] = MM(a[0][1], B[0][1], acc[(MH)*4+0][(NB)+0]); \
  acc[(MH)*4+0][(NB)+1] = MM(a[0][1], B[1][1], acc[(MH)*4+0][(NB)+1]); \
  acc[(MH)*4+1][(NB)+0] = MM(a[1][1], B[0][1], acc[(MH)*4+1][(NB)+0]); \
  acc[(MH)*4+1][(NB)+1] = MM(a[1][1], B[1][1], acc[(MH)*4+1][(NB)+1]); \
  acc[(MH)*4+2][(NB)+0] = MM(a[2][1], B[0][1], acc[(MH)*4+2][(NB)+0]); \
  acc[(MH)*4+2][(NB)+1] = MM(a[2][1], B[1][1], acc[(MH)*4+2][(NB)+1]); \
  acc[(MH)*4+3][(NB)+0] = MM(a[3][1], B[0][1], acc[(MH)*4+3][(NB)+0]); \
  acc[(MH)*4+3][(NB)+1] = MM(a[3][1], B[1][1], acc[(MH)*4+3][(NB)+1]); \
  __builtin_amdgcn_s_setprio(0)

// One-barrier bodies: [BAR; WAITL; MFMA(p); RD(p+1); STAGE; WAITV].
#define PH0(CUR, S, KA1, WV) \
  BAR; WAITL; MF16(0, b0, 0); \
  RD_B(CUR,1,b1); \
  if (S) { STAGEA_TO((CUR)^1, 1, 0, KA1); STAGEA_TO((CUR)^1, 1, 1, KA1); } \
  WV

#define PH1(CUR, S, KT2, WV) \
  BAR; WAITL; MF16(0, b1, 2); \
  RD_A(CUR,1); \
  if (S) { STAGEA_TO(CUR, 0, 0, KT2); STAGEA_TO(CUR, 0, 1, KT2); } \
  WV

#define PH2(CUR, S, KT2, WV) \
  BAR; WAITL; MF16(1, b0, 0); \
  if (S) { STAGEB_TO(CUR, 0, 0, KT2); STAGEB_TO(CUR, 0, 1, KT2); } \
  WV

#define PH3(CUR, RDN, S, KT2, WV) \
  BAR; WAITL; MF16(1, b1, 2); \
  if (RDN) { RD_A((CUR)^1,0); RD_B((CUR)^1,0,b0); } \
  if (S) { STAGEB_TO(CUR, 1, 0, KT2); STAGEB_TO(CUR, 1, 1, KT2); } \
  WV

__global__ __launch_bounds__(512, 2)
void k_gemm_shift8(const unsigned short* __restrict__ A,   // 16384x2048 bf16 x
                   const unsigned short* __restrict__ Bw,  // 2048x2048 bf16 W_shift
                   const float* __restrict__ gate,
                   unsigned short* __restrict__ out) {     // x_shift bf16
  __shared__ __align__(16) unsigned char smem_raw[131072];
  unsigned short* smem = (unsigned short*)smem_raw;

  const int tid = threadIdx.x;
  const int lane = tid & 63;
  const int w = tid >> 6;
  const int wr = w >> 2, wc = w & 3;
  const int lr = lane & 15, lq = lane >> 4;
  const int bid = blockIdx.x;
  const int nblk = bid & 7, mblk = bid >> 3;   // XCD keeps one N-panel L2-resident
  const int m0 = mblk * 256, n0 = nblk * 256;

  // staging addressing (pre-swizzled global source; linear LDS dest)
  const int r0 = tid >> 3;                                   // 0..63
  const int colel = ((tid & 7) * 8) ^ (((tid >> 3) & 7) << 3);
  const unsigned short* aS = A + (size_t)((m0 ^ 1024) + r0) * 2048 + colel;  // roll fused
  const unsigned short* bS = Bw + (size_t)(n0 + ((tid >> 8) << 6) + (r0 & 31)) * 2048 + colel;
  const int ldsAst = tid * 8;
  const int ldsBst = ((tid >> 8) << 12) + (tid & 255) * 8;

  // ds_read addressing (swizzled)
  const int ardb = (wr * 128 + lr) * 64;
  const int brdb = (wc * 64 + lr) * 64;
  const int colrd0 = (lq * 8) ^ ((lr & 7) << 3);
  const int colrd1 = (32 + lq * 8) ^ ((lr & 7) << 3);

  short8 a[4][2], b0[2][2], b1[2][2];
  f32x4 acc[8][4] = {};

  // prologue: tile0 (all 4 halves) then tile1's Ah0,Bh0,Bh1
  STAGEA_TO(0,0,0,0); STAGEA_TO(0,0,1,0);
  STAGEB_TO(0,0,0,0); STAGEB_TO(0,0,1,0);
  STAGEB_TO(0,1,0,0); STAGEB_TO(0,1,1,0);
  STAGEA_TO(0,1,0,0); STAGEA_TO(0,1,1,0);
  STAGEA_TO(1,0,0,64); STAGEA_TO(1,0,1,64);
  STAGEB_TO(1,0,0,64); STAGEB_TO(1,0,1,64);
  STAGEB_TO(1,1,0,64); STAGEB_TO(1,1,1,64);
  WAITV(6); BAR;
  RD_A(0,0); RD_B(0,0,b0);     // regs for tile0 P0

  int ka1 = 64, kt2 = 128;
  for (int j = 0; j < 15; ++j) {     // tiles 0..29
    PH0(0, 1, ka1, WAITV(8)); PH1(0, 1, kt2, WAITV(8));
    PH2(0, 1, kt2, WAITV(8)); PH3(0, 1, 1, kt2, WAITV(8));
    ka1 += 64; kt2 += 64;
    PH0(1, 1, ka1, WAITV(8)); PH1(1, 1, kt2, WAITV(8));
    PH2(1, 1, kt2, WAITV(8)); PH3(1, 1, 1, kt2, WAITV(8));
    ka1 += 64; kt2 += 64;
  }
  // tile 30 (CUR=0): stage only Ah1(31); tail waits
  PH0(0, 1, 1984, WAITV(8)); PH1(0, 0, 0, NOWV);
  PH2(0, 0, 0, WAITV(4));    PH3(0, 1, 0, 0, WAITV(2));
  // tile 31 (CUR=1): drain
  PH0(1, 0, 0, WAITV(0));    PH1(1, 0, 0, NOWV);
  PH2(1, 0, 0, NOWV);        PH3(1, 0, 0, 0, NOWV);

  // ---- epilogue: LDS transpose + fused sigmoid-gate blend, bf16 stores ----
  float* cbuf = (float*)smem_raw;                 // 64 x 260 f32
#pragma unroll
  for (int q = 0; q < 4; ++q) {
    __syncthreads();
    if (wr == (q >> 1)) {
#pragma unroll
      for (int mm = 0; mm < 4; ++mm) {
#pragma unroll
        for (int nf = 0; nf < 4; ++nf) {
#pragma unroll
          for (int i = 0; i < 4; ++i) {
            int rl = mm * 16 + lq * 4 + i;
            int cl = wc * 64 + nf * 16 + lr;
            cbuf[rl * 260 + cl] = acc[(q & 1) * 4 + mm][nf][i];
          }
        }
      }
    }
    __syncthreads();
#pragma unroll
    for (int it = 0; it < 4; ++it) {
      int idx = tid + it * 512;
      int rl = idx >> 5, cb = (idx & 31) * 8;
      int gr = m0 + q * 64 + rl, gc = n0 + cb;
      f32x4 c0 = *(const f32x4*)&cbuf[rl * 260 + cb];
      f32x4 c1 = *(const f32x4*)&cbuf[rl * 260 + cb + 4];
      f32x4 g0 = *(const f32x4*)&gate[gc];
      f32x4 g1 = *(const f32x4*)&gate[gc + 4];
      bfu8 xv = *(const bfu8*)(A + (size_t)gr * 2048 + gc);
      bfu8 o;
#pragma unroll
      for (int jj = 0; jj < 4; ++jj) {
        float g = 1.f / (1.f + __expf(-g0[jj]));
        o[jj] = f2bf(c0[jj] * g + bf2f(xv[jj]) * (1.f - g));
        float h = 1.f / (1.f + __expf(-g1[jj]));
        o[jj + 4] = f2bf(c1[jj] * h + bf2f(xv[jj + 4]) * (1.f - h));
      }
      *(bfu8*)(out + (size_t)gr * 2048 + gc) = o;
    }
  }
}

// ---------------- fused LN-stats + kv GEMM on x_shift with affine LN correction ----------------
__launch_bounds__(256, 3)
__global__ void k_gemm_kv_f(const unsigned short* __restrict__ A,     // x_shift bf16
                            const unsigned short* __restrict__ Bw,    // G = gamma*Wkv interleaved
                            const float2* __restrict__ cgb,           // per-col (cg, cb)
                            const float* __restrict__ tfirst,
                            float* __restrict__ wkv) {
  __shared__ __align__(16) unsigned short As[32 * 32];
  __shared__ __align__(16) unsigned short Bs[128 * 32];
  __shared__ float2 rowst[32];
  const int tid = threadIdx.x;
  const int lane = tid & 63;
  const int wcv = tid >> 6;
  const int m0 = blockIdx.x * 32;
  const int lr = lane & 15, lk = (lane >> 4) << 3;
  const int c1 = tid, c2 = tid + 256;

  // ---- prologue: per-row mean/var (8 lanes per row, shfl reduce) ----
  {
    int r = tid >> 3, c8 = tid & 7;
    const unsigned short* row = A + (size_t)(m0 + r) * kD;
    float s = 0.f, q = 0.f;
#pragma unroll 4
    for (int i = 0; i < 32; ++i) {
      bfu8 v = *(const bfu8*)(row + (c8 + i * 8) * 8);
#pragma unroll
      for (int j = 0; j < 8; ++j) { float f = bf2f(v[j]); s += f; q += f * f; }
    }
    s += __shfl_xor(s, 1); q += __shfl_xor(q, 1);
    s += __shfl_xor(s, 2); q += __shfl_xor(q, 2);
    s += __shfl_xor(s, 4); q += __shfl_xor(q, 4);
    if (c8 == 0) {
      float mu = s * (1.f / kD);
      float var = q * (1.f / kD) - mu * mu;
      rowst[r] = make_float2(mu, rsqrtf(var + 1e-5f));
    }
  }

  const unsigned short* ga = A + (size_t)(m0 + (tid >> 2)) * kD + ((tid & 3) << 3);
  const unsigned short* gb0 = Bw + (size_t)(c1 >> 2) * kD + ((c1 & 3) << 3);
  const unsigned short* gb1 = Bw + (size_t)(c2 >> 2) * kD + ((c2 & 3) << 3);
  unsigned short* la = As + tid * 8;
  unsigned short* lb0 = Bs + c1 * 8;
  unsigned short* lb1 = Bs + c2 * 8;

  f32x4 acc[2][2] = {};

  for (int kt = 0; kt < kD; kt += 32) {
    __syncthreads();
    if (tid < 128) gload16(ga + kt, la);
    gload16(gb0 + kt, lb0);
    gload16(gb1 + kt, lb1);
    __syncthreads();
    short8 af[2], bf[2];
#pragma unroll
    for (int mf = 0; mf < 2; ++mf)
      af[mf] = *(const short8*)&As[(mf * 16 + lr) * 32 + lk];
#pragma unroll
    for (int nf = 0; nf < 2; ++nf)
      bf[nf] = *(const short8*)&Bs[(wcv * 32 + nf * 16 + lr) * 32 + lk];
#pragma unroll
    for (int mf = 0; mf < 2; ++mf)
#pragma unroll
      for (int nf = 0; nf < 2; ++nf)
        acc[mf][nf] = __builtin_amdgcn_mfma_f32_16x16x32_bf16(af[mf], bf[nf], acc[mf][nf], 0, 0, 0);
  }

  const int fq = lane >> 4, fr = lane & 15;
#pragma unroll
  for (int mf = 0; mf < 2; ++mf) {
#pragma unroll
    for (int nf = 0; nf < 2; ++nf) {
      int c = wcv * 32 + nf * 16 + fr;
      float2 gc = cgb[c];
#pragma unroll
      for (int i = 0; i < 4; ++i) {
        int rloc = mf * 16 + fq * 4 + i;
        float2 st = rowst[rloc];
        float val = st.y * (acc[mf][nf][i] - st.x * gc.x) + gc.y;  // LN-corrected k or v
        float other = __shfl_xor(val, 1);
        if (!(c & 1)) {
          int s = c >> 1;
          float sk = 1.f / (1.f + expf(-val));
          float u = expf(tfirst[s]);
          wkv[(size_t)(m0 + rloc) * kDS + s] = expf(-u * sk) * other;
        }
      }
    }
  }
}

// ---------------- chunked linear scan (chunk=64, warmup 256) -> bf16 states ----------------
__global__ void k_scan(const float* __restrict__ wkv, const float* __restrict__ tdec,
                       unsigned short* __restrict__ states, float* __restrict__ last_state) {
  int chunk = blockIdx.x;   // 0..31
  int b = blockIdx.y;       // 0..7
  int s = threadIdx.x;      // 0..63
  float w = expf(tdec[s]);
  int t1 = chunk * 64;
  int warm = t1 < 256 ? t1 : 256;
  const float* base = wkv + (size_t)b * kNT * kDS + s;
  unsigned short* sbase = states + (size_t)b * kNT * kDS + s;
  float st = 0.f;
#pragma unroll 4
  for (int t = t1 - warm; t < t1; ++t) st = fmaf(st, w, base[(size_t)t * kDS]);
#pragma unroll 4
  for (int t = t1; t < t1 + 64; ++t) {
    st = fmaf(st, w, base[(size_t)t * kDS]);
    sbase[(size_t)t * kDS] = f2bf(st);
  }
  if (chunk == 31) last_state[b * kDS + s] = st;
}

// ---------------- output GEMM (bf16 MFMA, f32 out): 128x128 tiles, K=64 ----------------
__launch_bounds__(256, 3)
__global__ void k_out_gemm(const unsigned short* __restrict__ states,  // 16384x64 bf16
                           const unsigned short* __restrict__ Wo,      // 2048x64 bf16
                           float* __restrict__ out) {
  __shared__ __align__(16) unsigned char sraw[33792];
  unsigned short* As = (unsigned short*)sraw;          // 128*64 bf16 = 16384 B
  unsigned short* Bs = As + 8192;                      // 16384 B
  float* cbuf = (float*)sraw;                          // aliases As/Bs after fragment reads
  const int tid = threadIdx.x;
  const int lane = tid & 63;
  const int w = tid >> 6;
  const int wr = w >> 1, wc = w & 1;
  const int lr = lane & 15, lq = lane >> 4;
  const int n0 = blockIdx.x * 128;
  const int m0 = blockIdx.y * 128;

  const int sr0 = tid >> 3;
  const int scol = ((tid & 7) * 8) ^ (((tid >> 3) & 7) << 3);
#pragma unroll
  for (int rd = 0; rd < 4; ++rd) {
    gload16(states + (size_t)(m0 + sr0 + rd * 32) * 64 + scol, As + tid * 8 + rd * 2048);
    gload16(Wo + (size_t)(n0 + sr0 + rd * 32) * 64 + scol, Bs + tid * 8 + rd * 2048);
  }
  __syncthreads();

  short8 a[4][2], b[4][2];
#pragma unroll
  for (int mf = 0; mf < 4; ++mf) {
#pragma unroll
    for (int ks = 0; ks < 2; ++ks) {
      int col = (ks * 32 + lq * 8) ^ ((lr & 7) << 3);
      a[mf][ks] = *(const short8*)&As[(wr * 64 + mf * 16 + lr) * 64 + col];
      b[mf][ks] = *(const short8*)&Bs[(wc * 64 + mf * 16 + lr) * 64 + col];
    }
  }
  f32x4 acc[4][4] = {};
#pragma unroll
  for (int mf = 0; mf < 4; ++mf)
#pragma unroll
    for (int nf = 0; nf < 4; ++nf) {
      acc[mf][nf] = __builtin_amdgcn_mfma_f32_16x16x32_bf16(a[mf][0], b[nf][0], acc[mf][nf], 0, 0, 0);
      acc[mf][nf] = __builtin_amdgcn_mfma_f32_16x16x32_bf16(a[mf][1], b[nf][1], acc[mf][nf], 0, 0, 0);
    }

#pragma unroll
  for (int q = 0; q < 2; ++q) {
    __syncthreads();
    if (wr == q) {
#pragma unroll
      for (int mf = 0; mf < 4; ++mf)
#pragma unroll
        for (int nf = 0; nf < 4; ++nf)
#pragma unroll
          for (int i = 0; i < 4; ++i) {
            int rl = mf * 16 + lq * 4 + i;
            int cl = wc * 64 + nf * 16 + lr;
            cbuf[rl * 132 + cl] = acc[mf][nf][i];
          }
    }
    __syncthreads();
#pragma unroll
    for (int it = 0; it < 8; ++it) {
      int idx = tid + it * 256;
      int rl = idx >> 5, cb = (idx & 31) * 4;
      *(f32x4*)&out[(size_t)(m0 + q * 64 + rl) * kD + n0 + cb] = *(const f32x4*)&cbuf[rl * 132 + cb];
    }
  }
}

// ---------------- launcher ----------------
extern "C" void kernel_launch(void* const* d_in, const int* in_sizes, int n_in,
                              void* d_out, int out_size, void* d_ws, size_t ws_size,
                              hipStream_t stream) {
  const float* x    = (const float*)d_in[0];
  const float* Wk   = (const float*)d_in[1];
  const float* Wv   = (const float*)d_in[2];
  const float* Wo   = (const float*)d_in[3];
  const float* Wsh  = (const float*)d_in[4];
  const float* gate = (const float*)d_in[5];
  const float* tdec = (const float*)d_in[6];
  const float* tfir = (const float*)d_in[7];
  const float* lng  = (const float*)d_in[8];
  const float* lnb  = (const float*)d_in[9];
  float* out = (float*)d_out;
  char* ws = (char*)d_ws;

  unsigned short* xbf   = (unsigned short*)(ws);               // 67108864 B (x bf16)
  unsigned short* wshbf = (unsigned short*)(ws + 67108864);    //  8388608 B
  unsigned short* wkvbf = (unsigned short*)(ws + 75497472);    //   524288 B (G interleaved)
  float* wkvf           = (float*)(ws + 76021760);             //  4194304 B
  unsigned short* stbf  = (unsigned short*)(ws + 80216064);    //  2097152 B (states bf16)
  unsigned short* wobf  = (unsigned short*)(ws + 82313216);    //   262144 B (Wo bf16)
  float2* cgbp          = (float2*)(ws + 82575360);            //     1024 B (cg, cb per col)

  k_prep<<<18624, 256, 0, stream>>>(x, Wsh, Wo, Wk, Wv, lng, lnb,
                                    xbf, wshbf, wobf, wkvbf, cgbp);

  // x_shift (bf16) staged in d_out, overwritten later by the final output GEMM
  k_gemm_shift8<<<512, 512, 0, stream>>>(xbf, wshbf, gate, (unsigned short*)out);
  k_gemm_kv_f<<<512, 256, 0, stream>>>((const unsigned short*)out, wkvbf, cgbp, tfir, wkvf);
  k_scan<<<dim3(32, 8), 64, 0, stream>>>(wkvf, tdec, stbf, out + kOutElems);
  k_out_gemm<<<dim3(16, 128), 256, 0, stream>>>(stbf, wobf, out);
}